// Round 1
// baseline (1751.348 us; speedup 1.0000x reference)
//
#include <hip/hip_runtime.h>
#include <hip/hip_bf16.h>
#include <math.h>

#define N_NODES 50000
#define N_EDGES 800000
#define F_IN    256
#define H_DIM   128
#define D_DIM   64
#define MAX_LOGSTD 10.0f
#define LEAKY_SLOPE 0.01f

// ---------- helpers ----------
__device__ inline void atomicMaxFloat(float* addr, float val) {
    // IEEE-754 monotonic int trick: non-negative floats order as ints,
    // negative floats order reversed as uints.
    if (val >= 0.0f) atomicMax((int*)addr, __float_as_int(val));
    else             atomicMin((unsigned int*)addr, __float_as_uint(val));
}

// ---------- GCN: h0 = x @ W_gcn  (N x 256 @ 256 x 128) ----------
__global__ void k_gemm_gcn(const float* __restrict__ x, const float* __restrict__ W,
                           float* __restrict__ h0) {
    __shared__ float xs[F_IN];
    int row = blockIdx.x;
    int j = threadIdx.x;            // 0..127
    xs[j]       = x[row * F_IN + j];
    xs[j + 128] = x[row * F_IN + j + 128];
    __syncthreads();
    float acc = 0.f;
#pragma unroll 8
    for (int k = 0; k < F_IN; ++k) acc = fmaf(xs[k], W[k * H_DIM + j], acc);
    h0[row * H_DIM + j] = acc;
}

// ---------- degree (incl. self loop) ----------
__global__ void k_deg_init(float* __restrict__ deg) {
    int i = blockIdx.x * blockDim.x + threadIdx.x;
    if (i < N_NODES) deg[i] = 1.0f;     // self loop contributes 1
}
__global__ void k_deg_acc(const int* __restrict__ dst, float* __restrict__ deg) {
    int e = blockIdx.x * blockDim.x + threadIdx.x;
    if (e < N_EDGES) atomicAdd(&deg[dst[e]], 1.0f);
}
__global__ void k_rsqrt(float* __restrict__ deg) {
    int i = blockIdx.x * blockDim.x + threadIdx.x;
    if (i < N_NODES) deg[i] = rsqrtf(deg[i]);   // deg >= 1 always
}

// ---------- GCN aggregate ----------
__global__ void k_gcn_self(const float* __restrict__ h0, const float* __restrict__ dinv,
                           float* __restrict__ h) {
    int idx = blockIdx.x * blockDim.x + threadIdx.x;
    if (idx < N_NODES * H_DIM) {
        int i = idx >> 7;
        float d = dinv[i];
        h[idx] = h0[idx] * d * d;   // self-loop term initializes accumulator
    }
}
__global__ void k_gcn_scatter(const float* __restrict__ h0, const int* __restrict__ src,
                              const int* __restrict__ dst, const float* __restrict__ dinv,
                              float* __restrict__ h) {
    int tid = blockIdx.x * blockDim.x + threadIdx.x;
    int e = tid >> 7;               // 128 threads per edge
    int j = tid & 127;
    if (e >= N_EDGES) return;
    int s = src[e], d = dst[e];
    float c = dinv[s] * dinv[d];
    atomicAdd(&h[d * H_DIM + j], h0[s * H_DIM + j] * c);
}
__global__ void k_bias_leaky(float* __restrict__ h, const float* __restrict__ b) {
    int idx = blockIdx.x * blockDim.x + threadIdx.x;
    if (idx < N_NODES * H_DIM) {
        float v = h[idx] + b[idx & 127];
        h[idx] = (v >= 0.f) ? v : LEAKY_SLOPE * v;
    }
}

// ---------- TransformerConv: q,k,v to ws; skip (h@Ws+bs) straight to out ----------
__global__ void k_qkvs(const float* __restrict__ h,
                       const float* __restrict__ Wq, const float* __restrict__ bq,
                       const float* __restrict__ Wk, const float* __restrict__ bk,
                       const float* __restrict__ Wv, const float* __restrict__ bv,
                       const float* __restrict__ Ws, const float* __restrict__ bs,
                       float* __restrict__ q, float* __restrict__ k,
                       float* __restrict__ v, float* __restrict__ outp) {
    __shared__ float hs[H_DIM];
    int row = blockIdx.x;
    int t = threadIdx.x;            // 0..255
    if (t < H_DIM) hs[t] = h[row * H_DIM + t];
    __syncthreads();
    int grp = t >> 6;               // 0:q 1:k 2:v 3:skip
    int j = t & 63;
    const float* W = (grp == 0) ? Wq : (grp == 1) ? Wk : (grp == 2) ? Wv : Ws;
    const float* b = (grp == 0) ? bq : (grp == 1) ? bk : (grp == 2) ? bv : bs;
    float acc = b[j];
#pragma unroll 8
    for (int kk = 0; kk < H_DIM; ++kk) acc = fmaf(hs[kk], W[kk * D_DIM + j], acc);
    float* o = (grp == 0) ? q : (grp == 1) ? k : (grp == 2) ? v : outp;
    o[row * D_DIM + j] = acc;
}

__global__ void k_amax_init(float* __restrict__ amax, float* __restrict__ denom) {
    int i = blockIdx.x * blockDim.x + threadIdx.x;
    if (i < N_NODES) { amax[i] = -INFINITY; denom[i] = 0.f; }
}

// alpha_e = dot(q[dst], k[src]) / 8 ; amax[dst] = max(alpha)
__global__ void k_alpha(const float* __restrict__ q, const float* __restrict__ k,
                        const int* __restrict__ src, const int* __restrict__ dst,
                        float* __restrict__ w, float* __restrict__ amax) {
    int tid = blockIdx.x * blockDim.x + threadIdx.x;
    int e = tid >> 6;               // one wave (64 lanes) per edge
    int l = tid & 63;
    if (e >= N_EDGES) return;
    int s = src[e], d = dst[e];
    float p = q[d * D_DIM + l] * k[s * D_DIM + l];
#pragma unroll
    for (int off = 32; off >= 1; off >>= 1) p += __shfl_xor(p, off, 64);
    if (l == 0) {
        float alpha = p * 0.125f;   // 1/sqrt(64)
        w[e] = alpha;
        atomicMaxFloat(&amax[d], alpha);
    }
}

__global__ void k_ex(const int* __restrict__ dst, const float* __restrict__ amax,
                     float* __restrict__ w, float* __restrict__ denom) {
    int e = blockIdx.x * blockDim.x + threadIdx.x;
    if (e >= N_EDGES) return;
    int d = dst[e];
    float ex = expf(w[e] - amax[d]);
    w[e] = ex;
    atomicAdd(&denom[d], ex);
}

__global__ void k_pv(const float* __restrict__ v, const int* __restrict__ src,
                     const int* __restrict__ dst, const float* __restrict__ w,
                     const float* __restrict__ denom, float* __restrict__ outp) {
    int tid = blockIdx.x * blockDim.x + threadIdx.x;
    int e = tid >> 6;               // 64 threads per edge
    int j = tid & 63;
    if (e >= N_EDGES) return;
    int s = src[e], d = dst[e];
    float wt = w[e] / (denom[d] + 1e-16f);
    atomicAdd(&outp[d * D_DIM + j], v[s * D_DIM + j] * wt);
}

__global__ void k_clamp(float* __restrict__ o) {
    int i = blockIdx.x * blockDim.x + threadIdx.x;
    if (i < N_NODES * D_DIM) o[i] = fminf(o[i], MAX_LOGSTD);
}

// ---------- launch ----------
extern "C" void kernel_launch(void* const* d_in, const int* in_sizes, int n_in,
                              void* d_out, int out_size, void* d_ws, size_t ws_size,
                              hipStream_t stream) {
    const float* x     = (const float*)d_in[0];
    const int*   ei    = (const int*)d_in[1];
    const int*   src   = ei;
    const int*   dst   = ei + N_EDGES;
    const float* W_gcn = (const float*)d_in[2];
    const float* b_gcn = (const float*)d_in[3];

    // per-conv weight sets: [Wq,bq,Wk,bk,Wv,bv,Ws,bs] starting at 4 (mu) and 12 (ls)
    const float* Wm[8]; const float* Wl[8];
    for (int i = 0; i < 8; ++i) { Wm[i] = (const float*)d_in[4 + i]; Wl[i] = (const float*)d_in[12 + i]; }

    float* out    = (float*)d_out;
    float* mu_out = out;
    float* ls_out = out + N_NODES * D_DIM;

    float* ws    = (float*)d_ws;
    float* h0    = ws;                      // N*H
    float* h     = h0 + N_NODES * H_DIM;    // N*H
    float* dinv  = h + N_NODES * H_DIM;     // N  (also used as deg)
    float* amax  = dinv + N_NODES;          // N
    float* denom = amax + N_NODES;          // N
    float* q     = denom + N_NODES;         // N*D
    float* k     = q + N_NODES * D_DIM;     // N*D
    float* v     = k + N_NODES * D_DIM;     // N*D
    float* w     = v + N_NODES * D_DIM;     // E

    const int B = 256;
    // GCN
    k_gemm_gcn<<<N_NODES, 128, 0, stream>>>(x, W_gcn, h0);
    k_deg_init<<<(N_NODES + B - 1) / B, B, 0, stream>>>(dinv);
    k_deg_acc<<<(N_EDGES + B - 1) / B, B, 0, stream>>>(dst, dinv);
    k_rsqrt<<<(N_NODES + B - 1) / B, B, 0, stream>>>(dinv);
    k_gcn_self<<<(N_NODES * H_DIM + B - 1) / B, B, 0, stream>>>(h0, dinv, h);
    k_gcn_scatter<<<(N_EDGES * 128) / B, B, 0, stream>>>(h0, src, dst, dinv, h);
    k_bias_leaky<<<(N_NODES * H_DIM + B - 1) / B, B, 0, stream>>>(h, b_gcn);

    // two TransformerConvs
    for (int c = 0; c < 2; ++c) {
        const float* const* Wset = (c == 0) ? Wm : Wl;
        float* outp = (c == 0) ? mu_out : ls_out;
        k_qkvs<<<N_NODES, 256, 0, stream>>>(h, Wset[0], Wset[1], Wset[2], Wset[3],
                                            Wset[4], Wset[5], Wset[6], Wset[7],
                                            q, k, v, outp);
        k_amax_init<<<(N_NODES + B - 1) / B, B, 0, stream>>>(amax, denom);
        k_alpha<<<(N_EDGES * 64) / B, B, 0, stream>>>(q, k, src, dst, w, amax);
        k_ex<<<(N_EDGES + B - 1) / B, B, 0, stream>>>(dst, amax, w, denom);
        k_pv<<<(N_EDGES * 64) / B, B, 0, stream>>>(v, src, dst, w, denom, outp);
    }
    k_clamp<<<(N_NODES * D_DIM + B - 1) / B, B, 0, stream>>>(ls_out);
}

// Round 2
// 1213.127 us; speedup vs baseline: 1.4437x; 1.4437x over previous
//
#include <hip/hip_runtime.h>
#include <math.h>

#define N_NODES 50000
#define N_EDGES 800000
#define F_IN    256
#define H_DIM   128
#define D_DIM   64
#define MAX_LOGSTD 10.0f
#define LEAKY_SLOPE 0.01f

// ================= CSR build (by dst) =================
__global__ void k_zero(int* __restrict__ c) {
    int i = blockIdx.x * blockDim.x + threadIdx.x;
    if (i < N_NODES) c[i] = 0;
}
__global__ void k_hist(const int* __restrict__ dst, int* __restrict__ c) {
    int e = blockIdx.x * blockDim.x + threadIdx.x;
    if (e < N_EDGES) atomicAdd(&c[dst[e]], 1);
}
// single-block exclusive scan of counts -> rowptr; also dinv = rsqrt(deg+1)
__global__ void k_scan(const int* __restrict__ counts, int* __restrict__ rowptr,
                       int* __restrict__ cursor, float* __restrict__ dinv) {
    __shared__ int sums[1024];
    int t = threadIdx.x;
    const int CH = (N_NODES + 1023) / 1024;     // 49
    int base = t * CH, s = 0;
    for (int i = 0; i < CH; ++i) { int idx = base + i; if (idx < N_NODES) s += counts[idx]; }
    sums[t] = s; __syncthreads();
    for (int off = 1; off < 1024; off <<= 1) {
        int v = (t >= off) ? sums[t - off] : 0;
        __syncthreads();
        sums[t] += v;
        __syncthreads();
    }
    int run = (t > 0) ? sums[t - 1] : 0;
    for (int i = 0; i < CH; ++i) {
        int idx = base + i;
        if (idx < N_NODES) {
            rowptr[idx] = run; cursor[idx] = run;
            int c = counts[idx];
            dinv[idx] = rsqrtf((float)(c + 1));   // +1 self loop
            run += c;
        }
    }
    if (t == 1023) rowptr[N_NODES] = sums[1023];
}
__global__ void k_fill(const int* __restrict__ src, const int* __restrict__ dst,
                       int* __restrict__ cursor, int* __restrict__ srcs) {
    int e = blockIdx.x * blockDim.x + threadIdx.x;
    if (e >= N_EDGES) return;
    int pos = atomicAdd(&cursor[dst[e]], 1);
    srcs[pos] = src[e];
}

// ================= GCN GEMM: h0s = (x @ W) * dinv[row]  =================
// W (256x128 fp32 = 128 KB) cached in LDS; 8 rows/iter; 4-row register block.
__global__ __launch_bounds__(256, 1) void k_gemm_gcn(
        const float* __restrict__ x, const float* __restrict__ W,
        const float* __restrict__ dinv, float* __restrict__ h0s) {
    __shared__ float Wl[F_IN * H_DIM];   // 128 KB
    __shared__ float xs[8][F_IN];        // 8 KB
    int t = threadIdx.x;
    for (int i = t; i < F_IN * H_DIM; i += 256) Wl[i] = W[i];
    __syncthreads();
    int j = t & 127, half = t >> 7;
    const int RPB = (N_NODES + 511) / 512;   // 98 rows per block
    int r0 = blockIdx.x * RPB, r1 = min(r0 + RPB, N_NODES);
    for (int rb = r0; rb < r1; rb += 8) {
        for (int i = t; i < 8 * F_IN; i += 256) {
            int r = i >> 8, c = i & 255;
            xs[r][c] = (rb + r < N_NODES) ? x[(rb + r) * F_IN + c] : 0.f;
        }
        __syncthreads();
        float acc[4] = {0.f, 0.f, 0.f, 0.f};
#pragma unroll 4
        for (int kk = 0; kk < F_IN; ++kk) {
            float wv = Wl[kk * H_DIM + j];
#pragma unroll
            for (int r = 0; r < 4; ++r) acc[r] = fmaf(xs[half * 4 + r][kk], wv, acc[r]);
        }
        __syncthreads();
#pragma unroll
        for (int r = 0; r < 4; ++r) {
            int row = rb + half * 4 + r;
            if (row < r1) h0s[row * H_DIM + j] = acc[r] * dinv[row];
        }
    }
}

// ================= GCN aggregate: gather over in-edges =================
// h[i] = leaky( (h0s[i] + sum_{s in N(i)} h0s[s]) * dinv[i] + b )
__global__ void k_gcn_gather(const float* __restrict__ h0s, const int* __restrict__ rowptr,
                             const int* __restrict__ srcs, const float* __restrict__ dinv,
                             const float* __restrict__ b, float* __restrict__ h) {
    int t = threadIdx.x;
    int node = blockIdx.x * 2 + (t >> 7);
    int j = t & 127;
    if (node >= N_NODES) return;
    float acc = h0s[node * H_DIM + j];        // self loop (dinv[node] folded in h0s)
    int beg = rowptr[node], end = rowptr[node + 1];
    for (int p = beg; p < end; ++p) {
        int s = srcs[p];
        acc += h0s[s * H_DIM + j];            // dinv[s] folded in h0s
    }
    float val = acc * dinv[node] + b[j];
    h[node * H_DIM + j] = (val >= 0.f) ? val : LEAKY_SLOPE * val;
}

// ================= q,k,v,skip GEMMs: all 4 W (128 KB) in LDS =================
__global__ __launch_bounds__(256, 1) void k_qkvs(
        const float* __restrict__ h,
        const float* __restrict__ Wq, const float* __restrict__ bq,
        const float* __restrict__ Wk, const float* __restrict__ bk,
        const float* __restrict__ Wv, const float* __restrict__ bv,
        const float* __restrict__ Ws, const float* __restrict__ bs,
        float* __restrict__ q, float* __restrict__ k,
        float* __restrict__ v, float* __restrict__ outp) {
    __shared__ float Wl[4][H_DIM * D_DIM];  // 128 KB
    __shared__ float xs[8][H_DIM];          // 4 KB
    int t = threadIdx.x;
    for (int i = t; i < H_DIM * D_DIM; i += 256) {
        Wl[0][i] = Wq[i]; Wl[1][i] = Wk[i]; Wl[2][i] = Wv[i]; Wl[3][i] = Ws[i];
    }
    __syncthreads();
    int grp = t >> 6, j = t & 63;           // wave-uniform grp
    const float* bptr = (grp == 0) ? bq : (grp == 1) ? bk : (grp == 2) ? bv : bs;
    float bj = bptr[j];
    float* optr = (grp == 0) ? q : (grp == 1) ? k : (grp == 2) ? v : outp;
    const int RPB = (N_NODES + 511) / 512;
    int r0 = blockIdx.x * RPB, r1 = min(r0 + RPB, N_NODES);
    for (int rb = r0; rb < r1; rb += 8) {
        for (int i = t; i < 8 * H_DIM; i += 256) {
            int r = i >> 7, c = i & 127;
            xs[r][c] = (rb + r < N_NODES) ? h[(rb + r) * H_DIM + c] : 0.f;
        }
        __syncthreads();
        float acc[8];
#pragma unroll
        for (int r = 0; r < 8; ++r) acc[r] = bj;
#pragma unroll 4
        for (int kk = 0; kk < H_DIM; ++kk) {
            float wv = Wl[grp][kk * D_DIM + j];
#pragma unroll
            for (int r = 0; r < 8; ++r) acc[r] = fmaf(xs[r][kk], wv, acc[r]);
        }
        __syncthreads();
#pragma unroll
        for (int r = 0; r < 8; ++r) {
            int row = rb + r;
            if (row < r1) optr[row * D_DIM + j] = acc[r];
        }
    }
}

// ================= fused attention: one wave per dst node =================
// online softmax over in-edges; out = acc/denom + skip (skip pre-stored in outp)
__global__ void k_attn(const float* __restrict__ q, const float* __restrict__ kf,
                       const float* __restrict__ vf, const int* __restrict__ rowptr,
                       const int* __restrict__ srcs, float* __restrict__ outp,
                       int clampFlag) {
    int t = threadIdx.x;
    int node = blockIdx.x * 4 + (t >> 6);
    int l = t & 63;
    if (node >= N_NODES) return;
    float ql = q[node * D_DIM + l];
    float m = -INFINITY, den = 0.f, acc = 0.f;
    int beg = rowptr[node], end = rowptr[node + 1];
    for (int p = beg; p < end; ++p) {
        int s = srcs[p];
        float d = ql * kf[s * D_DIM + l];
#pragma unroll
        for (int off = 32; off >= 1; off >>= 1) d += __shfl_xor(d, off, 64);
        float alpha = d * 0.125f;                 // / sqrt(64)
        float mn = fmaxf(m, alpha);
        float sc = __expf(m - mn);                // 0 on first edge (m=-inf)
        float ex = __expf(alpha - mn);
        den = den * sc + ex;
        acc = acc * sc + ex * vf[s * D_DIM + l];
        m = mn;
    }
    float o = acc / (den + 1e-16f) + outp[node * D_DIM + l];
    if (clampFlag) o = fminf(o, MAX_LOGSTD);
    outp[node * D_DIM + l] = o;
}

// ================= launch =================
extern "C" void kernel_launch(void* const* d_in, const int* in_sizes, int n_in,
                              void* d_out, int out_size, void* d_ws, size_t ws_size,
                              hipStream_t stream) {
    const float* x     = (const float*)d_in[0];
    const int*   ei    = (const int*)d_in[1];
    const int*   src   = ei;
    const int*   dst   = ei + N_EDGES;
    const float* W_gcn = (const float*)d_in[2];
    const float* b_gcn = (const float*)d_in[3];
    const float* Wm[8]; const float* Wl8[8];
    for (int i = 0; i < 8; ++i) { Wm[i] = (const float*)d_in[4 + i]; Wl8[i] = (const float*)d_in[12 + i]; }

    float* out    = (float*)d_out;
    float* mu_out = out;
    float* ls_out = out + N_NODES * D_DIM;

    float* ws   = (float*)d_ws;
    float* h0s  = ws;                        // N*H
    float* h    = h0s + N_NODES * H_DIM;     // N*H
    float* dinv = h + N_NODES * H_DIM;       // N
    float* q    = dinv + N_NODES;            // N*D
    float* k    = q + N_NODES * D_DIM;       // N*D
    float* v    = k + N_NODES * D_DIM;       // N*D
    int* counts = (int*)(v + N_NODES * D_DIM);   // N
    int* rowptr = counts + N_NODES;              // N+1
    int* cursor = rowptr + N_NODES + 1;          // N
    int* srcs   = cursor + N_NODES;              // E

    const int B = 256;
    // CSR build
    k_zero<<<(N_NODES + B - 1) / B, B, 0, stream>>>(counts);
    k_hist<<<(N_EDGES + B - 1) / B, B, 0, stream>>>(dst, counts);
    k_scan<<<1, 1024, 0, stream>>>(counts, rowptr, cursor, dinv);
    k_fill<<<(N_EDGES + B - 1) / B, B, 0, stream>>>(src, dst, cursor, srcs);

    // GCN
    k_gemm_gcn<<<512, 256, 0, stream>>>(x, W_gcn, dinv, h0s);
    k_gcn_gather<<<(N_NODES + 1) / 2, 256, 0, stream>>>(h0s, rowptr, srcs, dinv, b_gcn, h);

    // two TransformerConvs
    for (int c = 0; c < 2; ++c) {
        const float* const* Wset = (c == 0) ? Wm : Wl8;
        float* outp = (c == 0) ? mu_out : ls_out;
        k_qkvs<<<512, 256, 0, stream>>>(h, Wset[0], Wset[1], Wset[2], Wset[3],
                                        Wset[4], Wset[5], Wset[6], Wset[7],
                                        q, k, v, outp);
        k_attn<<<(N_NODES + 3) / 4, 256, 0, stream>>>(q, k, v, rowptr, srcs, outp, c);
    }
}

// Round 3
// 621.962 us; speedup vs baseline: 2.8158x; 1.9505x over previous
//
#include <hip/hip_runtime.h>
#include <math.h>

#define N_NODES 50000
#define N_EDGES 800000
#define F_IN    256
#define H_DIM   128
#define D_DIM   64
#define MAX_LOGSTD 10.0f
#define LEAKY_SLOPE 0.01f

// ================= CSR build (by dst) =================
__global__ void k_zero(int* __restrict__ c) {
    int i = blockIdx.x * blockDim.x + threadIdx.x;
    if (i < N_NODES) c[i] = 0;
}
__global__ void k_hist(const int* __restrict__ dst, int* __restrict__ c) {
    int e = blockIdx.x * blockDim.x + threadIdx.x;
    if (e < N_EDGES) atomicAdd(&c[dst[e]], 1);
}
__global__ void k_scan(const int* __restrict__ counts, int* __restrict__ rowptr,
                       int* __restrict__ cursor, float* __restrict__ dinv) {
    __shared__ int sums[1024];
    int t = threadIdx.x;
    const int CH = (N_NODES + 1023) / 1024;     // 49
    int base = t * CH, s = 0;
    for (int i = 0; i < CH; ++i) { int idx = base + i; if (idx < N_NODES) s += counts[idx]; }
    sums[t] = s; __syncthreads();
    for (int off = 1; off < 1024; off <<= 1) {
        int v = (t >= off) ? sums[t - off] : 0;
        __syncthreads();
        sums[t] += v;
        __syncthreads();
    }
    int run = (t > 0) ? sums[t - 1] : 0;
    for (int i = 0; i < CH; ++i) {
        int idx = base + i;
        if (idx < N_NODES) {
            rowptr[idx] = run; cursor[idx] = run;
            int c = counts[idx];
            dinv[idx] = rsqrtf((float)(c + 1));   // +1 self loop
            run += c;
        }
    }
    if (t == 1023) rowptr[N_NODES] = sums[1023];
}
__global__ void k_fill(const int* __restrict__ src, const int* __restrict__ dst,
                       int* __restrict__ cursor, int* __restrict__ srcs) {
    int e = blockIdx.x * blockDim.x + threadIdx.x;
    if (e >= N_EDGES) return;
    int pos = atomicAdd(&cursor[dst[e]], 1);
    srcs[pos] = src[e];
}

// ================= GCN GEMM: h0s = (x @ W) * dinv[row] =================
// 64x128 tile, BK=16, 256 threads, 4x8 register block. LDS ~12.4 KB.
#define BKG 16
__global__ __launch_bounds__(256) void k_gemm_gcn(
        const float* __restrict__ x, const float* __restrict__ W,
        const float* __restrict__ dinv, float* __restrict__ h0s) {
    __shared__ float xs[BKG][64 + 4];
    __shared__ float ws[BKG][H_DIM];
    int t = threadIdx.x;
    int tr = t & 15, tc = t >> 4;         // rows tr*4..+3, cols tc*8..+7
    int r0 = blockIdx.x * 64;
    int lj = t & 15, li = t >> 4;         // x-tile load coords
    float acc[4][8];
#pragma unroll
    for (int r = 0; r < 4; ++r)
#pragma unroll
        for (int c = 0; c < 8; ++c) acc[r][c] = 0.f;

    for (int k0 = 0; k0 < F_IN; k0 += BKG) {
#pragma unroll
        for (int pass = 0; pass < 4; ++pass) {
            int r = li + pass * 16;
            int row = r0 + r;
            xs[lj][r] = (row < N_NODES) ? x[row * F_IN + k0 + lj] : 0.f;
        }
#pragma unroll
        for (int p = 0; p < 8; ++p) {
            int idx = t + p * 256;        // 0..2047 over [16][128]
            int kk = idx >> 7, c = idx & 127;
            ws[kk][c] = W[(k0 + kk) * H_DIM + c];
        }
        __syncthreads();
#pragma unroll
        for (int kk = 0; kk < BKG; ++kk) {
            float4 xa = *(const float4*)&xs[kk][tr * 4];
            float4 wa = *(const float4*)&ws[kk][tc * 8];
            float4 wb = *(const float4*)&ws[kk][tc * 8 + 4];
            const float xv[4] = {xa.x, xa.y, xa.z, xa.w};
            const float wv[8] = {wa.x, wa.y, wa.z, wa.w, wb.x, wb.y, wb.z, wb.w};
#pragma unroll
            for (int r = 0; r < 4; ++r)
#pragma unroll
                for (int c = 0; c < 8; ++c)
                    acc[r][c] = fmaf(xv[r], wv[c], acc[r][c]);
        }
        __syncthreads();
    }
#pragma unroll
    for (int r = 0; r < 4; ++r) {
        int row = r0 + tr * 4 + r;
        if (row < N_NODES) {
            float dv = dinv[row];
            float4 o1 = make_float4(acc[r][0]*dv, acc[r][1]*dv, acc[r][2]*dv, acc[r][3]*dv);
            float4 o2 = make_float4(acc[r][4]*dv, acc[r][5]*dv, acc[r][6]*dv, acc[r][7]*dv);
            *(float4*)&h0s[row * H_DIM + tc * 8]     = o1;
            *(float4*)&h0s[row * H_DIM + tc * 8 + 4] = o2;
        }
    }
}

// ================= GCN aggregate: float4 gather =================
__global__ void k_gcn_gather(const float* __restrict__ h0s, const int* __restrict__ rowptr,
                             const int* __restrict__ srcs, const float* __restrict__ dinv,
                             const float* __restrict__ b, float* __restrict__ h) {
    int t = threadIdx.x;
    int node = blockIdx.x * 8 + (t >> 5);
    int c = t & 31;                                  // float4 index over 128
    if (node >= N_NODES) return;
    const float4* h04 = (const float4*)h0s;
    float4 acc = h04[node * 32 + c];                 // self loop
    int beg = rowptr[node], end = rowptr[node + 1];
    for (int p = beg; p < end; ++p) {
        int s = srcs[p];
        float4 hv = h04[s * 32 + c];
        acc.x += hv.x; acc.y += hv.y; acc.z += hv.z; acc.w += hv.w;
    }
    float dv = dinv[node];
    float4 bv = *(const float4*)&b[c * 4];
    float4 val = make_float4(acc.x*dv + bv.x, acc.y*dv + bv.y, acc.z*dv + bv.z, acc.w*dv + bv.w);
    val.x = (val.x >= 0.f) ? val.x : LEAKY_SLOPE * val.x;
    val.y = (val.y >= 0.f) ? val.y : LEAKY_SLOPE * val.y;
    val.z = (val.z >= 0.f) ? val.z : LEAKY_SLOPE * val.z;
    val.w = (val.w >= 0.f) ? val.w : LEAKY_SLOPE * val.w;
    ((float4*)h)[node * 32 + c] = val;
}

// ================= q,k,v,skip GEMM: 64x256 tile, BK=16, 8x8 block =======
#define BKQ 16
__global__ __launch_bounds__(256) void k_qkvs(
        const float* __restrict__ h,
        const float* __restrict__ Wq, const float* __restrict__ bq,
        const float* __restrict__ Wk, const float* __restrict__ bk,
        const float* __restrict__ Wv, const float* __restrict__ bv,
        const float* __restrict__ Ws, const float* __restrict__ bs,
        float* __restrict__ q, float* __restrict__ k,
        float* __restrict__ v, float* __restrict__ outp) {
    __shared__ float xs[BKQ][64 + 4];
    __shared__ float ws[BKQ][256];
    int t = threadIdx.x;
    int tr = t & 7, tc = t >> 3;          // rows tr*8..+7, cols tc*8..+7
    int r0 = blockIdx.x * 64;
    // weight-load mapping: fixed column per thread
    int wg = t >> 6, wc = t & 63;
    const float* Wsrc = (wg == 0) ? Wq : (wg == 1) ? Wk : (wg == 2) ? Wv : Ws;
    // output mapping (wave-uniform group)
    int col0 = tc * 8, og = col0 >> 6, lc = col0 & 63;
    const float* bptr = (og == 0) ? bq : (og == 1) ? bk : (og == 2) ? bv : bs;
    float* optr = (og == 0) ? q : (og == 1) ? k : (og == 2) ? v : outp;
    int lj = t & 15, li = t >> 4;
    float acc[8][8];
#pragma unroll
    for (int c = 0; c < 8; ++c) {
        float bv = bptr[lc + c];
#pragma unroll
        for (int r = 0; r < 8; ++r) acc[r][c] = bv;
    }
    for (int k0 = 0; k0 < H_DIM; k0 += BKQ) {
#pragma unroll
        for (int pass = 0; pass < 4; ++pass) {
            int r = li + pass * 16;
            int row = r0 + r;
            xs[lj][r] = (row < N_NODES) ? h[row * H_DIM + k0 + lj] : 0.f;
        }
#pragma unroll
        for (int p = 0; p < BKQ; ++p)
            ws[p][t] = Wsrc[(k0 + p) * D_DIM + wc];
        __syncthreads();
#pragma unroll
        for (int kk = 0; kk < BKQ; ++kk) {
            float4 xa = *(const float4*)&xs[kk][tr * 8];
            float4 xb = *(const float4*)&xs[kk][tr * 8 + 4];
            float4 wa = *(const float4*)&ws[kk][tc * 8];
            float4 wb = *(const float4*)&ws[kk][tc * 8 + 4];
            const float xv[8] = {xa.x, xa.y, xa.z, xa.w, xb.x, xb.y, xb.z, xb.w};
            const float wv[8] = {wa.x, wa.y, wa.z, wa.w, wb.x, wb.y, wb.z, wb.w};
#pragma unroll
            for (int r = 0; r < 8; ++r)
#pragma unroll
                for (int c = 0; c < 8; ++c)
                    acc[r][c] = fmaf(xv[r], wv[c], acc[r][c]);
        }
        __syncthreads();
    }
#pragma unroll
    for (int r = 0; r < 8; ++r) {
        int row = r0 + tr * 8 + r;
        if (row < N_NODES) {
            float4 o1 = make_float4(acc[r][0], acc[r][1], acc[r][2], acc[r][3]);
            float4 o2 = make_float4(acc[r][4], acc[r][5], acc[r][6], acc[r][7]);
            *(float4*)&optr[row * D_DIM + lc]     = o1;
            *(float4*)&optr[row * D_DIM + lc + 4] = o2;
        }
    }
}

// ================= fused attention: wave/node, 4x16-lane groups =========
__global__ void k_attn(const float* __restrict__ q, const float* __restrict__ kf,
                       const float* __restrict__ vf, const int* __restrict__ rowptr,
                       const int* __restrict__ srcs, float* __restrict__ outp,
                       int clampFlag) {
    int t = threadIdx.x;
    int node = blockIdx.x * 4 + (t >> 6);
    int l = t & 63;
    if (node >= N_NODES) return;
    int g = l >> 4, sl = l & 15;
    const float4* q4p = (const float4*)(q + node * D_DIM);
    float4 q4 = q4p[sl];
    int beg = rowptr[node], end = rowptr[node + 1];
    int deg = end - beg;
    int p0 = beg + ((deg * g) >> 2);
    int p1 = beg + ((deg * (g + 1)) >> 2);
    float m = -INFINITY, den = 0.f;
    float4 acc = make_float4(0.f, 0.f, 0.f, 0.f);
    for (int p = p0; p < p1; ++p) {
        int s = srcs[p];
        const float4* k4p = (const float4*)(kf + s * D_DIM);
        const float4* v4p = (const float4*)(vf + s * D_DIM);
        float4 k4 = k4p[sl];
        float4 v4 = v4p[sl];
        float d = q4.x * k4.x;
        d = fmaf(q4.y, k4.y, d);
        d = fmaf(q4.z, k4.z, d);
        d = fmaf(q4.w, k4.w, d);
        d += __shfl_xor(d, 1);
        d += __shfl_xor(d, 2);
        d += __shfl_xor(d, 4);
        d += __shfl_xor(d, 8);
        float alpha = d * 0.125f;                 // / sqrt(64)
        float mn = fmaxf(m, alpha);
        float sc = __expf(m - mn);                // 0 on first edge
        float ex = __expf(alpha - mn);
        den = den * sc + ex;
        acc.x = acc.x * sc + ex * v4.x;
        acc.y = acc.y * sc + ex * v4.y;
        acc.z = acc.z * sc + ex * v4.z;
        acc.w = acc.w * sc + ex * v4.w;
        m = mn;
    }
    // merge 4 group states (flash-style)
    float M = m;
    M = fmaxf(M, __shfl_xor(M, 16));
    M = fmaxf(M, __shfl_xor(M, 32));
    float sc = (m == -INFINITY) ? 0.f : __expf(m - M);
    den *= sc;
    acc.x *= sc; acc.y *= sc; acc.z *= sc; acc.w *= sc;
    den += __shfl_xor(den, 16);
    den += __shfl_xor(den, 32);
    acc.x += __shfl_xor(acc.x, 16); acc.x += __shfl_xor(acc.x, 32);
    acc.y += __shfl_xor(acc.y, 16); acc.y += __shfl_xor(acc.y, 32);
    acc.z += __shfl_xor(acc.z, 16); acc.z += __shfl_xor(acc.z, 32);
    acc.w += __shfl_xor(acc.w, 16); acc.w += __shfl_xor(acc.w, 32);
    if (g == 0) {
        float inv = 1.f / (den + 1e-16f);
        float4 sk = ((float4*)outp)[node * 16 + sl];
        float4 o = make_float4(acc.x * inv + sk.x, acc.y * inv + sk.y,
                               acc.z * inv + sk.z, acc.w * inv + sk.w);
        if (clampFlag) {
            o.x = fminf(o.x, MAX_LOGSTD); o.y = fminf(o.y, MAX_LOGSTD);
            o.z = fminf(o.z, MAX_LOGSTD); o.w = fminf(o.w, MAX_LOGSTD);
        }
        ((float4*)outp)[node * 16 + sl] = o;
    }
}

// ================= launch =================
extern "C" void kernel_launch(void* const* d_in, const int* in_sizes, int n_in,
                              void* d_out, int out_size, void* d_ws, size_t ws_size,
                              hipStream_t stream) {
    const float* x     = (const float*)d_in[0];
    const int*   ei    = (const int*)d_in[1];
    const int*   src   = ei;
    const int*   dst   = ei + N_EDGES;
    const float* W_gcn = (const float*)d_in[2];
    const float* b_gcn = (const float*)d_in[3];
    const float* Wm[8]; const float* Wl8[8];
    for (int i = 0; i < 8; ++i) { Wm[i] = (const float*)d_in[4 + i]; Wl8[i] = (const float*)d_in[12 + i]; }

    float* out    = (float*)d_out;
    float* mu_out = out;
    float* ls_out = out + N_NODES * D_DIM;

    float* ws   = (float*)d_ws;
    float* h0s  = ws;                        // N*H
    float* h    = h0s + N_NODES * H_DIM;     // N*H
    float* dinv = h + N_NODES * H_DIM;       // N
    float* q    = dinv + N_NODES;            // N*D
    float* k    = q + N_NODES * D_DIM;       // N*D
    float* v    = k + N_NODES * D_DIM;       // N*D
    int* counts = (int*)(v + N_NODES * D_DIM);   // N
    int* rowptr = counts + N_NODES;              // N+1
    int* cursor = rowptr + N_NODES + 1;          // N
    int* srcs   = cursor + N_NODES;              // E

    const int B = 256;
    // CSR build
    k_zero<<<(N_NODES + B - 1) / B, B, 0, stream>>>(counts);
    k_hist<<<(N_EDGES + B - 1) / B, B, 0, stream>>>(dst, counts);
    k_scan<<<1, 1024, 0, stream>>>(counts, rowptr, cursor, dinv);
    k_fill<<<(N_EDGES + B - 1) / B, B, 0, stream>>>(src, dst, cursor, srcs);

    // GCN
    k_gemm_gcn<<<(N_NODES + 63) / 64, 256, 0, stream>>>(x, W_gcn, dinv, h0s);
    k_gcn_gather<<<(N_NODES + 7) / 8, 256, 0, stream>>>(h0s, rowptr, srcs, dinv, b_gcn, h);

    // two TransformerConvs
    for (int c = 0; c < 2; ++c) {
        const float* const* Wset = (c == 0) ? Wm : Wl8;
        float* outp = (c == 0) ? mu_out : ls_out;
        k_qkvs<<<(N_NODES + 63) / 64, 256, 0, stream>>>(h, Wset[0], Wset[1], Wset[2], Wset[3],
                                                        Wset[4], Wset[5], Wset[6], Wset[7],
                                                        q, k, v, outp);
        k_attn<<<(N_NODES + 3) / 4, 256, 0, stream>>>(q, k, v, rowptr, srcs, outp, c);
    }
}

// Round 4
// 484.606 us; speedup vs baseline: 3.6140x; 1.2834x over previous
//
#include <hip/hip_runtime.h>
#include <math.h>

#define N_NODES 50000
#define N_EDGES 800000
#define F_IN    256
#define H_DIM   128
#define D_DIM   64
#define MAX_LOGSTD 10.0f
#define LEAKY_SLOPE 0.01f

#define N_INT4   12500          // N_NODES/4
#define SCAN_BLK 49             // ceil(N_INT4/256)

// ================= CSR build (by dst) =================
__global__ void k_zero(int* __restrict__ c) {
    int i = blockIdx.x * blockDim.x + threadIdx.x;
    if (i < N_NODES) c[i] = 0;
}
__global__ void k_hist(const int* __restrict__ dst, int* __restrict__ c) {
    int e = blockIdx.x * blockDim.x + threadIdx.x;
    if (e < N_EDGES) atomicAdd(&c[dst[e]], 1);
}
// phase 1: block-local exclusive scan of counts (int4 per thread) + block sums
__global__ void k_scan1(const int* __restrict__ counts, int* __restrict__ rowptr,
                        int* __restrict__ blockSums) {
    __shared__ int sc[256];
    int t = threadIdx.x, b = blockIdx.x;
    int idx4 = b * 256 + t;
    int4 c = make_int4(0, 0, 0, 0);
    if (idx4 < N_INT4) c = ((const int4*)counts)[idx4];
    int s = c.x + c.y + c.z + c.w;
    sc[t] = s; __syncthreads();
    for (int off = 1; off < 256; off <<= 1) {
        int v = (t >= off) ? sc[t - off] : 0;
        __syncthreads();
        sc[t] += v;
        __syncthreads();
    }
    int pre = (t > 0) ? sc[t - 1] : 0;
    if (idx4 < N_INT4) {
        int4 r;
        r.x = pre;
        r.y = r.x + c.x;
        r.z = r.y + c.y;
        r.w = r.z + c.z;
        ((int4*)rowptr)[idx4] = r;
    }
    if (t == 255) blockSums[b] = sc[255];
}
// phase 2: add block offset (each block redundantly reduces blockSums), emit
// final rowptr/cursor and dinv = rsqrt(deg+1)
__global__ void k_scan2(const int* __restrict__ counts, const int* __restrict__ blockSums,
                        int* __restrict__ rowptr, int* __restrict__ cursor,
                        float* __restrict__ dinv) {
    __shared__ int offS;
    int t = threadIdx.x, b = blockIdx.x;
    if (t < 64) {
        int v = (t < b) ? blockSums[t] : 0;   // b <= 48 < 64
#pragma unroll
        for (int off = 32; off >= 1; off >>= 1) v += __shfl_xor(v, off, 64);
        if (t == 0) offS = v;
    }
    __syncthreads();
    int off = offS;
    int idx4 = b * 256 + t;
    if (idx4 < N_INT4) {
        int4 c = ((const int4*)counts)[idx4];
        int4 r = ((const int4*)rowptr)[idx4];
        r.x += off; r.y += off; r.z += off; r.w += off;
        ((int4*)rowptr)[idx4] = r;
        ((int4*)cursor)[idx4] = r;
        float4 dv;
        dv.x = rsqrtf((float)(c.x + 1));
        dv.y = rsqrtf((float)(c.y + 1));
        dv.z = rsqrtf((float)(c.z + 1));
        dv.w = rsqrtf((float)(c.w + 1));
        ((float4*)dinv)[idx4] = dv;
    }
    if (b == 0 && t == 0) rowptr[N_NODES] = N_EDGES;
}
__global__ void k_fill(const int* __restrict__ src, const int* __restrict__ dst,
                       int* __restrict__ cursor, int* __restrict__ srcs) {
    int e = blockIdx.x * blockDim.x + threadIdx.x;
    if (e >= N_EDGES) return;
    int pos = atomicAdd(&cursor[dst[e]], 1);
    srcs[pos] = src[e];
}

// ================= GCN GEMM: h0s = (x @ W) * dinv[row] =================
// 64x128 tile, BK=16, 256 threads, 4x8 register block. LDS ~12.4 KB.
#define BKG 16
__global__ __launch_bounds__(256) void k_gemm_gcn(
        const float* __restrict__ x, const float* __restrict__ W,
        const float* __restrict__ dinv, float* __restrict__ h0s) {
    __shared__ float xs[BKG][64 + 4];
    __shared__ float ws[BKG][H_DIM];
    int t = threadIdx.x;
    int tr = t & 15, tc = t >> 4;         // rows tr*4..+3, cols tc*8..+7
    int r0 = blockIdx.x * 64;
    int lj = t & 15, li = t >> 4;         // x-tile load coords
    float acc[4][8];
#pragma unroll
    for (int r = 0; r < 4; ++r)
#pragma unroll
        for (int c = 0; c < 8; ++c) acc[r][c] = 0.f;

    for (int k0 = 0; k0 < F_IN; k0 += BKG) {
#pragma unroll
        for (int pass = 0; pass < 4; ++pass) {
            int r = li + pass * 16;
            int row = r0 + r;
            xs[lj][r] = (row < N_NODES) ? x[row * F_IN + k0 + lj] : 0.f;
        }
#pragma unroll
        for (int p = 0; p < 8; ++p) {
            int idx = t + p * 256;        // 0..2047 over [16][128]
            int kk = idx >> 7, c = idx & 127;
            ws[kk][c] = W[(k0 + kk) * H_DIM + c];
        }
        __syncthreads();
#pragma unroll
        for (int kk = 0; kk < BKG; ++kk) {
            float4 xa = *(const float4*)&xs[kk][tr * 4];
            float4 wa = *(const float4*)&ws[kk][tc * 8];
            float4 wb = *(const float4*)&ws[kk][tc * 8 + 4];
            const float xv[4] = {xa.x, xa.y, xa.z, xa.w};
            const float wv[8] = {wa.x, wa.y, wa.z, wa.w, wb.x, wb.y, wb.z, wb.w};
#pragma unroll
            for (int r = 0; r < 4; ++r)
#pragma unroll
                for (int c = 0; c < 8; ++c)
                    acc[r][c] = fmaf(xv[r], wv[c], acc[r][c]);
        }
        __syncthreads();
    }
#pragma unroll
    for (int r = 0; r < 4; ++r) {
        int row = r0 + tr * 4 + r;
        if (row < N_NODES) {
            float dv = dinv[row];
            float4 o1 = make_float4(acc[r][0]*dv, acc[r][1]*dv, acc[r][2]*dv, acc[r][3]*dv);
            float4 o2 = make_float4(acc[r][4]*dv, acc[r][5]*dv, acc[r][6]*dv, acc[r][7]*dv);
            *(float4*)&h0s[row * H_DIM + tc * 8]     = o1;
            *(float4*)&h0s[row * H_DIM + tc * 8 + 4] = o2;
        }
    }
}

// ================= GCN aggregate: float4 gather =================
__global__ void k_gcn_gather(const float* __restrict__ h0s, const int* __restrict__ rowptr,
                             const int* __restrict__ srcs, const float* __restrict__ dinv,
                             const float* __restrict__ b, float* __restrict__ h) {
    int t = threadIdx.x;
    int node = blockIdx.x * 8 + (t >> 5);
    int c = t & 31;                                  // float4 index over 128
    if (node >= N_NODES) return;
    const float4* h04 = (const float4*)h0s;
    float4 acc = h04[node * 32 + c];                 // self loop
    int beg = rowptr[node], end = rowptr[node + 1];
    for (int p = beg; p < end; ++p) {
        int s = srcs[p];
        float4 hv = h04[s * 32 + c];
        acc.x += hv.x; acc.y += hv.y; acc.z += hv.z; acc.w += hv.w;
    }
    float dv = dinv[node];
    float4 bv = *(const float4*)&b[c * 4];
    float4 val = make_float4(acc.x*dv + bv.x, acc.y*dv + bv.y, acc.z*dv + bv.z, acc.w*dv + bv.w);
    val.x = (val.x >= 0.f) ? val.x : LEAKY_SLOPE * val.x;
    val.y = (val.y >= 0.f) ? val.y : LEAKY_SLOPE * val.y;
    val.z = (val.z >= 0.f) ? val.z : LEAKY_SLOPE * val.z;
    val.w = (val.w >= 0.f) ? val.w : LEAKY_SLOPE * val.w;
    ((float4*)h)[node * 32 + c] = val;
}

// ================= q,k,v,skip GEMM: 64x256 tile, BK=16, 8x8 block =======
#define BKQ 16
__global__ __launch_bounds__(256) void k_qkvs(
        const float* __restrict__ h,
        const float* __restrict__ Wq, const float* __restrict__ bq,
        const float* __restrict__ Wk, const float* __restrict__ bk,
        const float* __restrict__ Wv, const float* __restrict__ bv,
        const float* __restrict__ Ws, const float* __restrict__ bs,
        float* __restrict__ q, float* __restrict__ k,
        float* __restrict__ v, float* __restrict__ outp) {
    __shared__ float xs[BKQ][64 + 4];
    __shared__ float ws[BKQ][256];
    int t = threadIdx.x;
    int tr = t & 7, tc = t >> 3;          // rows tr*8..+7, cols tc*8..+7
    int r0 = blockIdx.x * 64;
    // weight-load mapping: fixed column per thread
    int wg = t >> 6, wc = t & 63;
    const float* Wsrc = (wg == 0) ? Wq : (wg == 1) ? Wk : (wg == 2) ? Wv : Ws;
    // output mapping (wave-uniform group)
    int col0 = tc * 8, og = col0 >> 6, lc = col0 & 63;
    const float* bptr = (og == 0) ? bq : (og == 1) ? bk : (og == 2) ? bv : bs;
    float* optr = (og == 0) ? q : (og == 1) ? k : (og == 2) ? v : outp;
    int lj = t & 15, li = t >> 4;
    float acc[8][8];
#pragma unroll
    for (int c = 0; c < 8; ++c) {
        float bv = bptr[lc + c];
#pragma unroll
        for (int r = 0; r < 8; ++r) acc[r][c] = bv;
    }
    for (int k0 = 0; k0 < H_DIM; k0 += BKQ) {
#pragma unroll
        for (int pass = 0; pass < 4; ++pass) {
            int r = li + pass * 16;
            int row = r0 + r;
            xs[lj][r] = (row < N_NODES) ? h[row * H_DIM + k0 + lj] : 0.f;
        }
#pragma unroll
        for (int p = 0; p < BKQ; ++p)
            ws[p][t] = Wsrc[(k0 + p) * D_DIM + wc];
        __syncthreads();
#pragma unroll
        for (int kk = 0; kk < BKQ; ++kk) {
            float4 xa = *(const float4*)&xs[kk][tr * 8];
            float4 xb = *(const float4*)&xs[kk][tr * 8 + 4];
            float4 wa = *(const float4*)&ws[kk][tc * 8];
            float4 wb = *(const float4*)&ws[kk][tc * 8 + 4];
            const float xv[8] = {xa.x, xa.y, xa.z, xa.w, xb.x, xb.y, xb.z, xb.w};
            const float wv[8] = {wa.x, wa.y, wa.z, wa.w, wb.x, wb.y, wb.z, wb.w};
#pragma unroll
            for (int r = 0; r < 8; ++r)
#pragma unroll
                for (int c = 0; c < 8; ++c)
                    acc[r][c] = fmaf(xv[r], wv[c], acc[r][c]);
        }
        __syncthreads();
    }
#pragma unroll
    for (int r = 0; r < 8; ++r) {
        int row = r0 + tr * 8 + r;
        if (row < N_NODES) {
            float4 o1 = make_float4(acc[r][0], acc[r][1], acc[r][2], acc[r][3]);
            float4 o2 = make_float4(acc[r][4], acc[r][5], acc[r][6], acc[r][7]);
            *(float4*)&optr[row * D_DIM + lc]     = o1;
            *(float4*)&optr[row * D_DIM + lc + 4] = o2;
        }
    }
}

// ================= fused attention: wave/node, 4x16-lane groups =========
__global__ void k_attn(const float* __restrict__ q, const float* __restrict__ kf,
                       const float* __restrict__ vf, const int* __restrict__ rowptr,
                       const int* __restrict__ srcs, float* __restrict__ outp,
                       int clampFlag) {
    int t = threadIdx.x;
    int node = blockIdx.x * 4 + (t >> 6);
    int l = t & 63;
    if (node >= N_NODES) return;
    int g = l >> 4, sl = l & 15;
    const float4* q4p = (const float4*)(q + node * D_DIM);
    float4 q4 = q4p[sl];
    int beg = rowptr[node], end = rowptr[node + 1];
    int deg = end - beg;
    int p0 = beg + ((deg * g) >> 2);
    int p1 = beg + ((deg * (g + 1)) >> 2);
    float m = -INFINITY, den = 0.f;
    float4 acc = make_float4(0.f, 0.f, 0.f, 0.f);
    for (int p = p0; p < p1; ++p) {
        int s = srcs[p];
        const float4* k4p = (const float4*)(kf + s * D_DIM);
        const float4* v4p = (const float4*)(vf + s * D_DIM);
        float4 k4 = k4p[sl];
        float4 v4 = v4p[sl];
        float d = q4.x * k4.x;
        d = fmaf(q4.y, k4.y, d);
        d = fmaf(q4.z, k4.z, d);
        d = fmaf(q4.w, k4.w, d);
        d += __shfl_xor(d, 1);
        d += __shfl_xor(d, 2);
        d += __shfl_xor(d, 4);
        d += __shfl_xor(d, 8);
        float alpha = d * 0.125f;                 // / sqrt(64)
        float mn = fmaxf(m, alpha);
        float sc = __expf(m - mn);                // 0 on first edge
        float ex = __expf(alpha - mn);
        den = den * sc + ex;
        acc.x = acc.x * sc + ex * v4.x;
        acc.y = acc.y * sc + ex * v4.y;
        acc.z = acc.z * sc + ex * v4.z;
        acc.w = acc.w * sc + ex * v4.w;
        m = mn;
    }
    // merge 4 group states (flash-style)
    float M = m;
    M = fmaxf(M, __shfl_xor(M, 16));
    M = fmaxf(M, __shfl_xor(M, 32));
    float sc = (m == -INFINITY) ? 0.f : __expf(m - M);
    den *= sc;
    acc.x *= sc; acc.y *= sc; acc.z *= sc; acc.w *= sc;
    den += __shfl_xor(den, 16);
    den += __shfl_xor(den, 32);
    acc.x += __shfl_xor(acc.x, 16); acc.x += __shfl_xor(acc.x, 32);
    acc.y += __shfl_xor(acc.y, 16); acc.y += __shfl_xor(acc.y, 32);
    acc.z += __shfl_xor(acc.z, 16); acc.z += __shfl_xor(acc.z, 32);
    acc.w += __shfl_xor(acc.w, 16); acc.w += __shfl_xor(acc.w, 32);
    if (g == 0) {
        float inv = 1.f / (den + 1e-16f);
        float4 sk = ((float4*)outp)[node * 16 + sl];
        float4 o = make_float4(acc.x * inv + sk.x, acc.y * inv + sk.y,
                               acc.z * inv + sk.z, acc.w * inv + sk.w);
        if (clampFlag) {
            o.x = fminf(o.x, MAX_LOGSTD); o.y = fminf(o.y, MAX_LOGSTD);
            o.z = fminf(o.z, MAX_LOGSTD); o.w = fminf(o.w, MAX_LOGSTD);
        }
        ((float4*)outp)[node * 16 + sl] = o;
    }
}

// ================= launch =================
extern "C" void kernel_launch(void* const* d_in, const int* in_sizes, int n_in,
                              void* d_out, int out_size, void* d_ws, size_t ws_size,
                              hipStream_t stream) {
    const float* x     = (const float*)d_in[0];
    const int*   ei    = (const int*)d_in[1];
    const int*   src   = ei;
    const int*   dst   = ei + N_EDGES;
    const float* W_gcn = (const float*)d_in[2];
    const float* b_gcn = (const float*)d_in[3];
    const float* Wm[8]; const float* Wl8[8];
    for (int i = 0; i < 8; ++i) { Wm[i] = (const float*)d_in[4 + i]; Wl8[i] = (const float*)d_in[12 + i]; }

    float* out    = (float*)d_out;
    float* mu_out = out;
    float* ls_out = out + N_NODES * D_DIM;

    float* ws   = (float*)d_ws;
    float* h0s  = ws;                        // N*H
    float* h    = h0s + N_NODES * H_DIM;     // N*H
    float* dinv = h + N_NODES * H_DIM;       // N
    float* q    = dinv + N_NODES;            // N*D
    float* k    = q + N_NODES * D_DIM;       // N*D
    float* v    = k + N_NODES * D_DIM;       // N*D
    int* counts = (int*)(v + N_NODES * D_DIM);   // N
    int* rowptr = counts + N_NODES;              // N+1 (rounded to +4 below)
    int* cursor = rowptr + N_NODES + 4;          // N
    int* srcs   = cursor + N_NODES;              // E
    int* blockSums = srcs + N_EDGES;             // SCAN_BLK

    const int B = 256;
    // CSR build
    k_zero<<<(N_NODES + B - 1) / B, B, 0, stream>>>(counts);
    k_hist<<<(N_EDGES + B - 1) / B, B, 0, stream>>>(dst, counts);
    k_scan1<<<SCAN_BLK, B, 0, stream>>>(counts, rowptr, blockSums);
    k_scan2<<<SCAN_BLK, B, 0, stream>>>(counts, blockSums, rowptr, cursor, dinv);
    k_fill<<<(N_EDGES + B - 1) / B, B, 0, stream>>>(src, dst, cursor, srcs);

    // GCN
    k_gemm_gcn<<<(N_NODES + 63) / 64, 256, 0, stream>>>(x, W_gcn, dinv, h0s);
    k_gcn_gather<<<(N_NODES + 7) / 8, 256, 0, stream>>>(h0s, rowptr, srcs, dinv, b_gcn, h);

    // two TransformerConvs
    for (int c = 0; c < 2; ++c) {
        const float* const* Wset = (c == 0) ? Wm : Wl8;
        float* outp = (c == 0) ? mu_out : ls_out;
        k_qkvs<<<(N_NODES + 63) / 64, 256, 0, stream>>>(h, Wset[0], Wset[1], Wset[2], Wset[3],
                                                        Wset[4], Wset[5], Wset[6], Wset[7],
                                                        q, k, v, outp);
        k_attn<<<(N_NODES + 3) / 4, 256, 0, stream>>>(q, k, v, rowptr, srcs, outp, c);
    }
}

// Round 5
// 423.874 us; speedup vs baseline: 4.1318x; 1.1433x over previous
//
#include <hip/hip_runtime.h>
#include <math.h>

#define N_NODES 50000
#define N_EDGES 800000
#define F_IN    256
#define H_DIM   128
#define D_DIM   64
#define MAX_LOGSTD 10.0f
#define LEAKY_SLOPE 0.01f

#define N_INT4   12500          // N_NODES/4
#define SCAN_BLK 49             // ceil(N_INT4/256)

// ---------- bf16 helpers (RNE pack, shift unpack) ----------
__device__ inline float bflo(unsigned u) { return __uint_as_float(u << 16); }
__device__ inline float bfhi(unsigned u) { return __uint_as_float(u & 0xFFFF0000u); }
__device__ inline unsigned short f2bf(float f) {
    unsigned u = __float_as_uint(f);
    u += 0x7FFFu + ((u >> 16) & 1u);
    return (unsigned short)(u >> 16);
}
__device__ inline unsigned pack2(float a, float b) {
    return (unsigned)f2bf(a) | ((unsigned)f2bf(b) << 16);
}

// ================= CSR build (by dst) =================
__global__ void k_zero(int* __restrict__ c) {
    int i = blockIdx.x * blockDim.x + threadIdx.x;
    if (i < N_NODES) c[i] = 0;
}
__global__ void k_hist(const int* __restrict__ dst, int* __restrict__ c) {
    int e = blockIdx.x * blockDim.x + threadIdx.x;
    if (e < N_EDGES) atomicAdd(&c[dst[e]], 1);
}
__global__ void k_scan1(const int* __restrict__ counts, int* __restrict__ rowptr,
                        int* __restrict__ blockSums) {
    __shared__ int sc[256];
    int t = threadIdx.x, b = blockIdx.x;
    int idx4 = b * 256 + t;
    int4 c = make_int4(0, 0, 0, 0);
    if (idx4 < N_INT4) c = ((const int4*)counts)[idx4];
    int s = c.x + c.y + c.z + c.w;
    sc[t] = s; __syncthreads();
    for (int off = 1; off < 256; off <<= 1) {
        int v = (t >= off) ? sc[t - off] : 0;
        __syncthreads();
        sc[t] += v;
        __syncthreads();
    }
    int pre = (t > 0) ? sc[t - 1] : 0;
    if (idx4 < N_INT4) {
        int4 r;
        r.x = pre;
        r.y = r.x + c.x;
        r.z = r.y + c.y;
        r.w = r.z + c.z;
        ((int4*)rowptr)[idx4] = r;
    }
    if (t == 255) blockSums[b] = sc[255];
}
__global__ void k_scan2(const int* __restrict__ counts, const int* __restrict__ blockSums,
                        int* __restrict__ rowptr, int* __restrict__ cursor,
                        float* __restrict__ dinv) {
    __shared__ int offS;
    int t = threadIdx.x, b = blockIdx.x;
    if (t < 64) {
        int v = (t < b) ? blockSums[t] : 0;   // b <= 48 < 64
#pragma unroll
        for (int off = 32; off >= 1; off >>= 1) v += __shfl_xor(v, off, 64);
        if (t == 0) offS = v;
    }
    __syncthreads();
    int off = offS;
    int idx4 = b * 256 + t;
    if (idx4 < N_INT4) {
        int4 c = ((const int4*)counts)[idx4];
        int4 r = ((const int4*)rowptr)[idx4];
        r.x += off; r.y += off; r.z += off; r.w += off;
        ((int4*)rowptr)[idx4] = r;
        ((int4*)cursor)[idx4] = r;
        float4 dv;
        dv.x = rsqrtf((float)(c.x + 1));
        dv.y = rsqrtf((float)(c.y + 1));
        dv.z = rsqrtf((float)(c.z + 1));
        dv.w = rsqrtf((float)(c.w + 1));
        ((float4*)dinv)[idx4] = dv;
    }
    if (b == 0 && t == 0) rowptr[N_NODES] = N_EDGES;
}
__global__ void k_fill(const int* __restrict__ src, const int* __restrict__ dst,
                       int* __restrict__ cursor, int* __restrict__ srcs) {
    int e = blockIdx.x * blockDim.x + threadIdx.x;
    if (e >= N_EDGES) return;
    int pos = atomicAdd(&cursor[dst[e]], 1);
    srcs[pos] = src[e];
}

// ================= GCN GEMM: h0b = bf16((x @ W) * dinv[row]) =================
#define BKG 16
__global__ __launch_bounds__(256) void k_gemm_gcn(
        const float* __restrict__ x, const float* __restrict__ W,
        const float* __restrict__ dinv, unsigned short* __restrict__ h0b) {
    __shared__ float xs[BKG][64 + 4];
    __shared__ float ws[BKG][H_DIM];
    int t = threadIdx.x;
    int tr = t & 15, tc = t >> 4;         // rows tr*4..+3, cols tc*8..+7
    int r0 = blockIdx.x * 64;
    int lj = t & 15, li = t >> 4;
    float acc[4][8];
#pragma unroll
    for (int r = 0; r < 4; ++r)
#pragma unroll
        for (int c = 0; c < 8; ++c) acc[r][c] = 0.f;

    for (int k0 = 0; k0 < F_IN; k0 += BKG) {
#pragma unroll
        for (int pass = 0; pass < 4; ++pass) {
            int r = li + pass * 16;
            int row = r0 + r;
            xs[lj][r] = (row < N_NODES) ? x[row * F_IN + k0 + lj] : 0.f;
        }
#pragma unroll
        for (int p = 0; p < 8; ++p) {
            int idx = t + p * 256;
            int kk = idx >> 7, c = idx & 127;
            ws[kk][c] = W[(k0 + kk) * H_DIM + c];
        }
        __syncthreads();
#pragma unroll
        for (int kk = 0; kk < BKG; ++kk) {
            float4 xa = *(const float4*)&xs[kk][tr * 4];
            float4 wa = *(const float4*)&ws[kk][tc * 8];
            float4 wb = *(const float4*)&ws[kk][tc * 8 + 4];
            const float xv[4] = {xa.x, xa.y, xa.z, xa.w};
            const float wv[8] = {wa.x, wa.y, wa.z, wa.w, wb.x, wb.y, wb.z, wb.w};
#pragma unroll
            for (int r = 0; r < 4; ++r)
#pragma unroll
                for (int c = 0; c < 8; ++c)
                    acc[r][c] = fmaf(xv[r], wv[c], acc[r][c]);
        }
        __syncthreads();
    }
#pragma unroll
    for (int r = 0; r < 4; ++r) {
        int row = r0 + tr * 4 + r;
        if (row < N_NODES) {
            float dv = dinv[row];
            uint4 o;
            o.x = pack2(acc[r][0] * dv, acc[r][1] * dv);
            o.y = pack2(acc[r][2] * dv, acc[r][3] * dv);
            o.z = pack2(acc[r][4] * dv, acc[r][5] * dv);
            o.w = pack2(acc[r][6] * dv, acc[r][7] * dv);
            *(uint4*)(h0b + (size_t)row * H_DIM + tc * 8) = o;
        }
    }
}

// ================= GCN aggregate: bf16 gather, fp32 accumulate =================
// 16 lanes/node, each lane covers 8 cols (uint4 = 8 bf16).
__global__ void k_gcn_gather(const unsigned short* __restrict__ h0b,
                             const int* __restrict__ rowptr, const int* __restrict__ srcs,
                             const float* __restrict__ dinv, const float* __restrict__ b,
                             float* __restrict__ h) {
    int t = threadIdx.x;
    int node = blockIdx.x * 16 + (t >> 4);
    int sl = t & 15;
    if (node >= N_NODES) return;
    uint4 U = ((const uint4*)(h0b + (size_t)node * H_DIM))[sl];   // self loop
    float acc[8] = {bflo(U.x), bfhi(U.x), bflo(U.y), bfhi(U.y),
                    bflo(U.z), bfhi(U.z), bflo(U.w), bfhi(U.w)};
    int beg = rowptr[node], end = rowptr[node + 1];
    for (int p = beg; p < end; ++p) {
        int s = srcs[p];
        uint4 V = ((const uint4*)(h0b + (size_t)s * H_DIM))[sl];
        acc[0] += bflo(V.x); acc[1] += bfhi(V.x);
        acc[2] += bflo(V.y); acc[3] += bfhi(V.y);
        acc[4] += bflo(V.z); acc[5] += bfhi(V.z);
        acc[6] += bflo(V.w); acc[7] += bfhi(V.w);
    }
    float dv = dinv[node];
    float out[8];
#pragma unroll
    for (int i = 0; i < 8; ++i) {
        float val = acc[i] * dv + b[sl * 8 + i];
        out[i] = (val >= 0.f) ? val : LEAKY_SLOPE * val;
    }
    float* hp = h + (size_t)node * H_DIM + sl * 8;
    *(float4*)hp       = make_float4(out[0], out[1], out[2], out[3]);
    *(float4*)(hp + 4) = make_float4(out[4], out[5], out[6], out[7]);
}

// ================= q,k,v,skip GEMM: q/skip fp32, k|v packed bf16 row =======
#define BKQ 16
__global__ __launch_bounds__(256) void k_qkvs(
        const float* __restrict__ h,
        const float* __restrict__ Wq, const float* __restrict__ bq,
        const float* __restrict__ Wk, const float* __restrict__ bk,
        const float* __restrict__ Wv, const float* __restrict__ bv,
        const float* __restrict__ Ws, const float* __restrict__ bs,
        float* __restrict__ q, unsigned short* __restrict__ kvb,
        float* __restrict__ outp) {
    __shared__ float xs[BKQ][64 + 4];
    __shared__ float ws[BKQ][256];
    int t = threadIdx.x;
    int tr = t & 7, tc = t >> 3;
    int r0 = blockIdx.x * 64;
    int wg = t >> 6, wc = t & 63;
    const float* Wsrc = (wg == 0) ? Wq : (wg == 1) ? Wk : (wg == 2) ? Wv : Ws;
    int col0 = tc * 8, og = col0 >> 6, lc = col0 & 63;   // wave-uniform og
    const float* bptr = (og == 0) ? bq : (og == 1) ? bk : (og == 2) ? bv : bs;
    int lj = t & 15, li = t >> 4;
    float acc[8][8];
#pragma unroll
    for (int c = 0; c < 8; ++c) {
        float bv = bptr[lc + c];
#pragma unroll
        for (int r = 0; r < 8; ++r) acc[r][c] = bv;
    }
    for (int k0 = 0; k0 < H_DIM; k0 += BKQ) {
#pragma unroll
        for (int pass = 0; pass < 4; ++pass) {
            int r = li + pass * 16;
            int row = r0 + r;
            xs[lj][r] = (row < N_NODES) ? h[row * H_DIM + k0 + lj] : 0.f;
        }
#pragma unroll
        for (int p = 0; p < BKQ; ++p)
            ws[p][t] = Wsrc[(k0 + p) * D_DIM + wc];
        __syncthreads();
#pragma unroll
        for (int kk = 0; kk < BKQ; ++kk) {
            float4 xa = *(const float4*)&xs[kk][tr * 8];
            float4 xb = *(const float4*)&xs[kk][tr * 8 + 4];
            float4 wa = *(const float4*)&ws[kk][tc * 8];
            float4 wb = *(const float4*)&ws[kk][tc * 8 + 4];
            const float xv[8] = {xa.x, xa.y, xa.z, xa.w, xb.x, xb.y, xb.z, xb.w};
            const float wv[8] = {wa.x, wa.y, wa.z, wa.w, wb.x, wb.y, wb.z, wb.w};
#pragma unroll
            for (int r = 0; r < 8; ++r)
#pragma unroll
                for (int c = 0; c < 8; ++c)
                    acc[r][c] = fmaf(xv[r], wv[c], acc[r][c]);
        }
        __syncthreads();
    }
    if (og == 0 || og == 3) {
        float* optr = (og == 0) ? q : outp;
#pragma unroll
        for (int r = 0; r < 8; ++r) {
            int row = r0 + tr * 8 + r;
            if (row < N_NODES) {
                *(float4*)&optr[(size_t)row * D_DIM + lc] =
                    make_float4(acc[r][0], acc[r][1], acc[r][2], acc[r][3]);
                *(float4*)&optr[(size_t)row * D_DIM + lc + 4] =
                    make_float4(acc[r][4], acc[r][5], acc[r][6], acc[r][7]);
            }
        }
    } else {
        int half = (og == 2) ? 64 : 0;    // k in first 128 B, v in second
#pragma unroll
        for (int r = 0; r < 8; ++r) {
            int row = r0 + tr * 8 + r;
            if (row < N_NODES) {
                uint4 o;
                o.x = pack2(acc[r][0], acc[r][1]);
                o.y = pack2(acc[r][2], acc[r][3]);
                o.z = pack2(acc[r][4], acc[r][5]);
                o.w = pack2(acc[r][6], acc[r][7]);
                *(uint4*)(kvb + (size_t)row * 128 + half + lc) = o;
            }
        }
    }
}

// ================= fused attention: wave/node, bf16 kv gather =========
__global__ void k_attn(const float* __restrict__ q, const unsigned short* __restrict__ kvb,
                       const int* __restrict__ rowptr, const int* __restrict__ srcs,
                       float* __restrict__ outp, int clampFlag) {
    int t = threadIdx.x;
    int node = blockIdx.x * 4 + (t >> 6);
    int l = t & 63;
    if (node >= N_NODES) return;
    int g = l >> 4, sl = l & 15;
    float4 q4 = ((const float4*)(q + (size_t)node * D_DIM))[sl];
    int beg = rowptr[node], end = rowptr[node + 1];
    int deg = end - beg;
    int p0 = beg + ((deg * g) >> 2);
    int p1 = beg + ((deg * (g + 1)) >> 2);
    float m = -INFINITY, den = 0.f;
    float4 acc = make_float4(0.f, 0.f, 0.f, 0.f);
    for (int p = p0; p < p1; ++p) {
        int s = srcs[p];
        const unsigned short* kv = kvb + (size_t)s * 128;
        uint2 ku = *(const uint2*)(kv + sl * 4);        // k elems sl*4..+3
        uint2 vu = *(const uint2*)(kv + 64 + sl * 4);   // v elems sl*4..+3
        float d = q4.x * bflo(ku.x);
        d = fmaf(q4.y, bfhi(ku.x), d);
        d = fmaf(q4.z, bflo(ku.y), d);
        d = fmaf(q4.w, bfhi(ku.y), d);
        d += __shfl_xor(d, 1);
        d += __shfl_xor(d, 2);
        d += __shfl_xor(d, 4);
        d += __shfl_xor(d, 8);
        float alpha = d * 0.125f;                 // / sqrt(64)
        float mn = fmaxf(m, alpha);
        float sc = __expf(m - mn);                // 0 on first edge
        float ex = __expf(alpha - mn);
        den = den * sc + ex;
        acc.x = acc.x * sc + ex * bflo(vu.x);
        acc.y = acc.y * sc + ex * bfhi(vu.x);
        acc.z = acc.z * sc + ex * bflo(vu.y);
        acc.w = acc.w * sc + ex * bfhi(vu.y);
        m = mn;
    }
    // merge 4 group states (flash-style)
    float M = m;
    M = fmaxf(M, __shfl_xor(M, 16));
    M = fmaxf(M, __shfl_xor(M, 32));
    float sc = (m == -INFINITY) ? 0.f : __expf(m - M);
    den *= sc;
    acc.x *= sc; acc.y *= sc; acc.z *= sc; acc.w *= sc;
    den += __shfl_xor(den, 16);
    den += __shfl_xor(den, 32);
    acc.x += __shfl_xor(acc.x, 16); acc.x += __shfl_xor(acc.x, 32);
    acc.y += __shfl_xor(acc.y, 16); acc.y += __shfl_xor(acc.y, 32);
    acc.z += __shfl_xor(acc.z, 16); acc.z += __shfl_xor(acc.z, 32);
    acc.w += __shfl_xor(acc.w, 16); acc.w += __shfl_xor(acc.w, 32);
    if (g == 0) {
        float inv = 1.f / (den + 1e-16f);
        float4 sk = ((float4*)outp)[node * 16 + sl];
        float4 o = make_float4(acc.x * inv + sk.x, acc.y * inv + sk.y,
                               acc.z * inv + sk.z, acc.w * inv + sk.w);
        if (clampFlag) {
            o.x = fminf(o.x, MAX_LOGSTD); o.y = fminf(o.y, MAX_LOGSTD);
            o.z = fminf(o.z, MAX_LOGSTD); o.w = fminf(o.w, MAX_LOGSTD);
        }
        ((float4*)outp)[node * 16 + sl] = o;
    }
}

// ================= launch =================
extern "C" void kernel_launch(void* const* d_in, const int* in_sizes, int n_in,
                              void* d_out, int out_size, void* d_ws, size_t ws_size,
                              hipStream_t stream) {
    const float* x     = (const float*)d_in[0];
    const int*   ei    = (const int*)d_in[1];
    const int*   src   = ei;
    const int*   dst   = ei + N_EDGES;
    const float* W_gcn = (const float*)d_in[2];
    const float* b_gcn = (const float*)d_in[3];
    const float* Wm[8]; const float* Wl8[8];
    for (int i = 0; i < 8; ++i) { Wm[i] = (const float*)d_in[4 + i]; Wl8[i] = (const float*)d_in[12 + i]; }

    float* out    = (float*)d_out;
    float* mu_out = out;
    float* ls_out = out + N_NODES * D_DIM;

    float* ws   = (float*)d_ws;
    float* h    = ws;                         // N*H fp32
    float* q    = h + (size_t)N_NODES * H_DIM;        // N*D fp32
    float* dinv = q + (size_t)N_NODES * D_DIM;        // N fp32
    unsigned short* h0b = (unsigned short*)(dinv + N_NODES);       // N*128 bf16
    unsigned short* kvb = h0b + (size_t)N_NODES * H_DIM;           // N*128 bf16
    int* counts = (int*)(kvb + (size_t)N_NODES * H_DIM);  // N
    int* rowptr = counts + N_NODES;               // N+4
    int* cursor = rowptr + N_NODES + 4;           // N
    int* srcs   = cursor + N_NODES;               // E
    int* blockSums = srcs + N_EDGES;              // SCAN_BLK

    const int B = 256;
    // CSR build
    k_zero<<<(N_NODES + B - 1) / B, B, 0, stream>>>(counts);
    k_hist<<<(N_EDGES + B - 1) / B, B, 0, stream>>>(dst, counts);
    k_scan1<<<SCAN_BLK, B, 0, stream>>>(counts, rowptr, blockSums);
    k_scan2<<<SCAN_BLK, B, 0, stream>>>(counts, blockSums, rowptr, cursor, dinv);
    k_fill<<<(N_EDGES + B - 1) / B, B, 0, stream>>>(src, dst, cursor, srcs);

    // GCN
    k_gemm_gcn<<<(N_NODES + 63) / 64, 256, 0, stream>>>(x, W_gcn, dinv, h0b);
    k_gcn_gather<<<(N_NODES + 15) / 16, 256, 0, stream>>>(h0b, rowptr, srcs, dinv, b_gcn, h);

    // two TransformerConvs
    for (int c = 0; c < 2; ++c) {
        const float* const* Wset = (c == 0) ? Wm : Wl8;
        float* outp = (c == 0) ? mu_out : ls_out;
        k_qkvs<<<(N_NODES + 63) / 64, 256, 0, stream>>>(h, Wset[0], Wset[1], Wset[2], Wset[3],
                                                        Wset[4], Wset[5], Wset[6], Wset[7],
                                                        q, kvb, outp);
        k_attn<<<(N_NODES + 3) / 4, 256, 0, stream>>>(q, kvb, rowptr, srcs, outp, c);
    }
}

// Round 6
// 309.564 us; speedup vs baseline: 5.6575x; 1.3693x over previous
//
#include <hip/hip_runtime.h>
#include <math.h>

#define N_NODES 50000
#define N_EDGES 800000
#define F_IN    256
#define H_DIM   128
#define D_DIM   64
#define MAX_LOGSTD 10.0f
#define LEAKY_SLOPE 0.01f

#define N_INT4   12500          // N_NODES/4
#define SCAN_BLK 49             // ceil(N_INT4/256)
#define GEMM_BLK 782            // ceil(N_NODES/64)

using bf16x8 = __attribute__((ext_vector_type(8))) short;
using f32x4  = __attribute__((ext_vector_type(4))) float;

// ---------- bf16 helpers (RNE pack, shift unpack) ----------
__device__ inline float bflo(unsigned u) { return __uint_as_float(u << 16); }
__device__ inline float bfhi(unsigned u) { return __uint_as_float(u & 0xFFFF0000u); }
__device__ inline unsigned short f2bf(float f) {
    unsigned u = __float_as_uint(f);
    u += 0x7FFFu + ((u >> 16) & 1u);
    return (unsigned short)(u >> 16);
}
__device__ inline unsigned pack2(float a, float b) {
    return (unsigned)f2bf(a) | ((unsigned)f2bf(b) << 16);
}

// ================= CSR build (by dst) =================
__global__ void k_zero(int* __restrict__ c) {
    int i = blockIdx.x * blockDim.x + threadIdx.x;
    if (i < N_NODES) c[i] = 0;
}
__global__ void k_hist(const int* __restrict__ dst, int* __restrict__ c) {
    int e = blockIdx.x * blockDim.x + threadIdx.x;
    if (e < N_EDGES) atomicAdd(&c[dst[e]], 1);
}
__global__ void k_scan1(const int* __restrict__ counts, int* __restrict__ rowptr,
                        int* __restrict__ blockSums) {
    __shared__ int sc[256];
    int t = threadIdx.x, b = blockIdx.x;
    int idx4 = b * 256 + t;
    int4 c = make_int4(0, 0, 0, 0);
    if (idx4 < N_INT4) c = ((const int4*)counts)[idx4];
    int s = c.x + c.y + c.z + c.w;
    sc[t] = s; __syncthreads();
    for (int off = 1; off < 256; off <<= 1) {
        int v = (t >= off) ? sc[t - off] : 0;
        __syncthreads();
        sc[t] += v;
        __syncthreads();
    }
    int pre = (t > 0) ? sc[t - 1] : 0;
    if (idx4 < N_INT4) {
        int4 r;
        r.x = pre;
        r.y = r.x + c.x;
        r.z = r.y + c.y;
        r.w = r.z + c.z;
        ((int4*)rowptr)[idx4] = r;
    }
    if (t == 255) blockSums[b] = sc[255];
}
__global__ void k_scan2(const int* __restrict__ counts, const int* __restrict__ blockSums,
                        int* __restrict__ rowptr, int* __restrict__ cursor,
                        float* __restrict__ dinv) {
    __shared__ int offS;
    int t = threadIdx.x, b = blockIdx.x;
    if (t < 64) {
        int v = (t < b) ? blockSums[t] : 0;   // b <= 48 < 64
#pragma unroll
        for (int off = 32; off >= 1; off >>= 1) v += __shfl_xor(v, off, 64);
        if (t == 0) offS = v;
    }
    __syncthreads();
    int off = offS;
    int idx4 = b * 256 + t;
    if (idx4 < N_INT4) {
        int4 c = ((const int4*)counts)[idx4];
        int4 r = ((const int4*)rowptr)[idx4];
        r.x += off; r.y += off; r.z += off; r.w += off;
        ((int4*)rowptr)[idx4] = r;
        ((int4*)cursor)[idx4] = r;
        float4 dv;
        dv.x = rsqrtf((float)(c.x + 1));
        dv.y = rsqrtf((float)(c.y + 1));
        dv.z = rsqrtf((float)(c.z + 1));
        dv.w = rsqrtf((float)(c.w + 1));
        ((float4*)dinv)[idx4] = dv;
    }
    if (b == 0 && t == 0) rowptr[N_NODES] = N_EDGES;
}
__global__ void k_fill(const int* __restrict__ src, const int* __restrict__ dst,
                       int* __restrict__ cursor, int* __restrict__ srcs) {
    int e = blockIdx.x * blockDim.x + threadIdx.x;
    if (e >= N_EDGES) return;
    int pos = atomicAdd(&cursor[dst[e]], 1);
    srcs[pos] = src[e];
}

// ================= conversions =================
// x fp32 -> bf16 (8 elems/thread)
__global__ void k_xcvt(const float* __restrict__ x, unsigned short* __restrict__ xb) {
    int i = blockIdx.x * blockDim.x + threadIdx.x;
    if (i >= N_NODES * F_IN / 8) return;
    const float4* xf = (const float4*)x;
    float4 a = xf[(size_t)i * 2], b = xf[(size_t)i * 2 + 1];
    uint4 o;
    o.x = pack2(a.x, a.y); o.y = pack2(a.z, a.w);
    o.z = pack2(b.x, b.y); o.w = pack2(b.z, b.w);
    ((uint4*)xb)[i] = o;
}
// W_gcn [256][128] fp32 -> per-lane fragment order: (((w*64+l)*8+ks)*2+ct)*8+j
__global__ void k_wfrag_gcn(const float* __restrict__ W, unsigned short* __restrict__ out) {
    int tid = blockIdx.x * 256 + threadIdx.x;
    if (tid >= 32768) return;
    int j = tid & 7, ct = (tid >> 3) & 1, ks = (tid >> 4) & 7;
    int l = (tid >> 7) & 63, w = tid >> 13;
    int k = ks * 32 + (l >> 4) * 8 + j;
    int n = w * 32 + ct * 16 + (l & 15);
    out[tid] = f2bf(W[k * H_DIM + n]);
}
// Wq/Wk/Wv/Ws [128][64] fp32 -> frag order: (((w*64+l)*4+ks)*4+ct)*8+j ; w selects matrix
__global__ void k_wfrag_qkvs(const float* __restrict__ Wq, const float* __restrict__ Wk,
                             const float* __restrict__ Wv, const float* __restrict__ Ws,
                             unsigned short* __restrict__ out) {
    int tid = blockIdx.x * 256 + threadIdx.x;
    if (tid >= 32768) return;
    int j = tid & 7, ct = (tid >> 3) & 3, ks = (tid >> 5) & 3;
    int l = (tid >> 7) & 63, w = tid >> 13;
    int k = ks * 32 + (l >> 4) * 8 + j;
    int n = ct * 16 + (l & 15);
    const float* Wsrc = (w == 0) ? Wq : (w == 1) ? Wk : (w == 2) ? Wv : Ws;
    out[tid] = f2bf(Wsrc[k * D_DIM + n]);
}

// ================= GCN GEMM (MFMA): h0b = bf16((x @ W) * dinv[row]) =================
// 64-row tile x 128 cols, K=256. 4 waves, each a 32-col strip. B frags in regs.
__global__ __launch_bounds__(256) void k_gemm_gcn_mfma(
        const unsigned short* __restrict__ xb, const unsigned short* __restrict__ wfrag,
        const float* __restrict__ dinv, unsigned short* __restrict__ h0b) {
    __shared__ uint4 sA[64 * 32];          // 64 rows x 256 bf16, XOR-swizzled
    int t = threadIdx.x, l = t & 63, w = t >> 6;
    int r0 = blockIdx.x * 64;
    const bf16x8* Wf = ((const bf16x8*)wfrag) + ((w * 64 + l) << 4);
    bf16x8 bfr[8][2];
#pragma unroll
    for (int ks = 0; ks < 8; ++ks) {
        bfr[ks][0] = Wf[ks * 2];
        bfr[ks][1] = Wf[ks * 2 + 1];
    }
    const uint4* xg = (const uint4*)xb;
#pragma unroll
    for (int p = 0; p < 8; ++p) {
        int idx = t + p * 256;
        int row = idx >> 5, c16 = idx & 31;
        int grow = min(r0 + row, N_NODES - 1);
        sA[row * 32 + (c16 ^ (row & 7))] = xg[(size_t)grow * 32 + c16];
    }
    __syncthreads();
    f32x4 zero = {0.f, 0.f, 0.f, 0.f};
    f32x4 acc[4][2];
#pragma unroll
    for (int rt = 0; rt < 4; ++rt) { acc[rt][0] = zero; acc[rt][1] = zero; }
    int lr = l & 15, lh = l >> 4;
#pragma unroll
    for (int ks = 0; ks < 8; ++ks) {
        bf16x8 a[4];
#pragma unroll
        for (int rt = 0; rt < 4; ++rt) {
            int row = rt * 16 + lr;
            int c4 = (ks * 4 + lh) ^ (row & 7);
            a[rt] = ((const bf16x8*)sA)[row * 32 + c4];
        }
#pragma unroll
        for (int rt = 0; rt < 4; ++rt) {
            acc[rt][0] = __builtin_amdgcn_mfma_f32_16x16x32_bf16(a[rt], bfr[ks][0], acc[rt][0], 0, 0, 0);
            acc[rt][1] = __builtin_amdgcn_mfma_f32_16x16x32_bf16(a[rt], bfr[ks][1], acc[rt][1], 0, 0, 0);
        }
    }
#pragma unroll
    for (int rt = 0; rt < 4; ++rt)
#pragma unroll
        for (int j = 0; j < 4; ++j) {
            int row = r0 + rt * 16 + lh * 4 + j;
            if (row < N_NODES) {
                float dv = dinv[row];
                size_t base = (size_t)row * H_DIM + w * 32 + lr;
                h0b[base]      = f2bf(acc[rt][0][j] * dv);
                h0b[base + 16] = f2bf(acc[rt][1][j] * dv);
            }
        }
}

// ================= GCN aggregate: bf16 gather -> bf16 h =================
__global__ void k_gcn_gather(const unsigned short* __restrict__ h0b,
                             const int* __restrict__ rowptr, const int* __restrict__ srcs,
                             const float* __restrict__ dinv, const float* __restrict__ b,
                             unsigned short* __restrict__ hb) {
    int t = threadIdx.x;
    int node = blockIdx.x * 16 + (t >> 4);
    int sl = t & 15;
    if (node >= N_NODES) return;
    uint4 U = ((const uint4*)(h0b + (size_t)node * H_DIM))[sl];   // self loop
    float acc[8] = {bflo(U.x), bfhi(U.x), bflo(U.y), bfhi(U.y),
                    bflo(U.z), bfhi(U.z), bflo(U.w), bfhi(U.w)};
    int beg = rowptr[node], end = rowptr[node + 1];
    for (int p = beg; p < end; ++p) {
        int s = srcs[p];
        uint4 V = ((const uint4*)(h0b + (size_t)s * H_DIM))[sl];
        acc[0] += bflo(V.x); acc[1] += bfhi(V.x);
        acc[2] += bflo(V.y); acc[3] += bfhi(V.y);
        acc[4] += bflo(V.z); acc[5] += bfhi(V.z);
        acc[6] += bflo(V.w); acc[7] += bfhi(V.w);
    }
    float dv = dinv[node];
    float out[8];
#pragma unroll
    for (int i = 0; i < 8; ++i) {
        float val = acc[i] * dv + b[sl * 8 + i];
        out[i] = (val >= 0.f) ? val : LEAKY_SLOPE * val;
    }
    uint4 o;
    o.x = pack2(out[0], out[1]); o.y = pack2(out[2], out[3]);
    o.z = pack2(out[4], out[5]); o.w = pack2(out[6], out[7]);
    ((uint4*)(hb + (size_t)node * H_DIM))[sl] = o;
}

// ============ q,k,v,skip GEMM (MFMA): wave w -> {q, k, v, skip} ============
// 64-row tile x 256 cols (4 mats side by side), K=128.
__global__ __launch_bounds__(256) void k_qkvs_mfma(
        const unsigned short* __restrict__ hb, const unsigned short* __restrict__ wfrag,
        const float* __restrict__ bq, const float* __restrict__ bk,
        const float* __restrict__ bv, const float* __restrict__ bs,
        float* __restrict__ q, unsigned short* __restrict__ kvb,
        float* __restrict__ outp) {
    __shared__ uint4 sA[64 * 16];          // 64 rows x 128 bf16, XOR-swizzled
    int t = threadIdx.x, l = t & 63, w = t >> 6;
    int r0 = blockIdx.x * 64;
    const bf16x8* Wf = ((const bf16x8*)wfrag) + ((w * 64 + l) << 4);
    bf16x8 bfr[4][4];
#pragma unroll
    for (int ks = 0; ks < 4; ++ks)
#pragma unroll
        for (int ct = 0; ct < 4; ++ct) bfr[ks][ct] = Wf[ks * 4 + ct];
    const uint4* hg = (const uint4*)hb;
#pragma unroll
    for (int p = 0; p < 4; ++p) {
        int idx = t + p * 256;
        int row = idx >> 4, c16 = idx & 15;
        int grow = min(r0 + row, N_NODES - 1);
        sA[row * 16 + (c16 ^ (row & 7))] = hg[(size_t)grow * 16 + c16];
    }
    __syncthreads();
    f32x4 zero = {0.f, 0.f, 0.f, 0.f};
    f32x4 acc[4][4];
#pragma unroll
    for (int rt = 0; rt < 4; ++rt)
#pragma unroll
        for (int ct = 0; ct < 4; ++ct) acc[rt][ct] = zero;
    int lr = l & 15, lh = l >> 4;
#pragma unroll
    for (int ks = 0; ks < 4; ++ks) {
        bf16x8 a[4];
#pragma unroll
        for (int rt = 0; rt < 4; ++rt) {
            int row = rt * 16 + lr;
            int c4 = (ks * 4 + lh) ^ (row & 7);
            a[rt] = ((const bf16x8*)sA)[row * 16 + c4];
        }
#pragma unroll
        for (int rt = 0; rt < 4; ++rt)
#pragma unroll
            for (int ct = 0; ct < 4; ++ct)
                acc[rt][ct] = __builtin_amdgcn_mfma_f32_16x16x32_bf16(a[rt], bfr[ks][ct], acc[rt][ct], 0, 0, 0);
    }
    const float* bias = (w == 0) ? bq : (w == 1) ? bk : (w == 2) ? bv : bs;
    float bcol[4];
#pragma unroll
    for (int ct = 0; ct < 4; ++ct) bcol[ct] = bias[ct * 16 + lr];
#pragma unroll
    for (int rt = 0; rt < 4; ++rt)
#pragma unroll
        for (int j = 0; j < 4; ++j) {
            int row = r0 + rt * 16 + lh * 4 + j;
            if (row >= N_NODES) continue;
            float v0 = acc[rt][0][j] + bcol[0];
            float v1 = acc[rt][1][j] + bcol[1];
            float v2 = acc[rt][2][j] + bcol[2];
            float v3 = acc[rt][3][j] + bcol[3];
            if (w == 0) {
                float* qp = q + (size_t)row * D_DIM + lr;
                qp[0] = v0; qp[16] = v1; qp[32] = v2; qp[48] = v3;
            } else if (w == 1) {
                unsigned short* kp = kvb + (size_t)row * 128 + lr;
                kp[0] = f2bf(v0); kp[16] = f2bf(v1); kp[32] = f2bf(v2); kp[48] = f2bf(v3);
            } else if (w == 2) {
                unsigned short* vp = kvb + (size_t)row * 128 + 64 + lr;
                vp[0] = f2bf(v0); vp[16] = f2bf(v1); vp[32] = f2bf(v2); vp[48] = f2bf(v3);
            } else {
                float* op = outp + (size_t)row * D_DIM + lr;
                op[0] = v0; op[16] = v1; op[32] = v2; op[48] = v3;
            }
        }
}

// ================= fused attention: wave/node, bf16 kv gather =========
__global__ void k_attn(const float* __restrict__ q, const unsigned short* __restrict__ kvb,
                       const int* __restrict__ rowptr, const int* __restrict__ srcs,
                       float* __restrict__ outp, int clampFlag) {
    int t = threadIdx.x;
    int node = blockIdx.x * 4 + (t >> 6);
    int l = t & 63;
    if (node >= N_NODES) return;
    int g = l >> 4, sl = l & 15;
    float4 q4 = ((const float4*)(q + (size_t)node * D_DIM))[sl];
    int beg = rowptr[node], end = rowptr[node + 1];
    int deg = end - beg;
    int p0 = beg + ((deg * g) >> 2);
    int p1 = beg + ((deg * (g + 1)) >> 2);
    float m = -INFINITY, den = 0.f;
    float4 acc = make_float4(0.f, 0.f, 0.f, 0.f);
    for (int p = p0; p < p1; ++p) {
        int s = srcs[p];
        const unsigned short* kv = kvb + (size_t)s * 128;
        uint2 ku = *(const uint2*)(kv + sl * 4);
        uint2 vu = *(const uint2*)(kv + 64 + sl * 4);
        float d = q4.x * bflo(ku.x);
        d = fmaf(q4.y, bfhi(ku.x), d);
        d = fmaf(q4.z, bflo(ku.y), d);
        d = fmaf(q4.w, bfhi(ku.y), d);
        d += __shfl_xor(d, 1);
        d += __shfl_xor(d, 2);
        d += __shfl_xor(d, 4);
        d += __shfl_xor(d, 8);
        float alpha = d * 0.125f;                 // / sqrt(64)
        float mn = fmaxf(m, alpha);
        float sc = __expf(m - mn);                // 0 on first edge
        float ex = __expf(alpha - mn);
        den = den * sc + ex;
        acc.x = acc.x * sc + ex * bflo(vu.x);
        acc.y = acc.y * sc + ex * bfhi(vu.x);
        acc.z = acc.z * sc + ex * bflo(vu.y);
        acc.w = acc.w * sc + ex * bfhi(vu.y);
        m = mn;
    }
    float M = m;
    M = fmaxf(M, __shfl_xor(M, 16));
    M = fmaxf(M, __shfl_xor(M, 32));
    float sc = (m == -INFINITY) ? 0.f : __expf(m - M);
    den *= sc;
    acc.x *= sc; acc.y *= sc; acc.z *= sc; acc.w *= sc;
    den += __shfl_xor(den, 16);
    den += __shfl_xor(den, 32);
    acc.x += __shfl_xor(acc.x, 16); acc.x += __shfl_xor(acc.x, 32);
    acc.y += __shfl_xor(acc.y, 16); acc.y += __shfl_xor(acc.y, 32);
    acc.z += __shfl_xor(acc.z, 16); acc.z += __shfl_xor(acc.z, 32);
    acc.w += __shfl_xor(acc.w, 16); acc.w += __shfl_xor(acc.w, 32);
    if (g == 0) {
        float inv = 1.f / (den + 1e-16f);
        float4 sk = ((float4*)outp)[node * 16 + sl];
        float4 o = make_float4(acc.x * inv + sk.x, acc.y * inv + sk.y,
                               acc.z * inv + sk.z, acc.w * inv + sk.w);
        if (clampFlag) {
            o.x = fminf(o.x, MAX_LOGSTD); o.y = fminf(o.y, MAX_LOGSTD);
            o.z = fminf(o.z, MAX_LOGSTD); o.w = fminf(o.w, MAX_LOGSTD);
        }
        ((float4*)outp)[node * 16 + sl] = o;
    }
}

// ================= launch =================
extern "C" void kernel_launch(void* const* d_in, const int* in_sizes, int n_in,
                              void* d_out, int out_size, void* d_ws, size_t ws_size,
                              hipStream_t stream) {
    const float* x     = (const float*)d_in[0];
    const int*   ei    = (const int*)d_in[1];
    const int*   src   = ei;
    const int*   dst   = ei + N_EDGES;
    const float* W_gcn = (const float*)d_in[2];
    const float* b_gcn = (const float*)d_in[3];
    const float* Wm[8]; const float* Wl8[8];
    for (int i = 0; i < 8; ++i) { Wm[i] = (const float*)d_in[4 + i]; Wl8[i] = (const float*)d_in[12 + i]; }

    float* out    = (float*)d_out;
    float* mu_out = out;
    float* ls_out = out + N_NODES * D_DIM;

    float* ws   = (float*)d_ws;
    float* q    = ws;                                          // N*64 fp32
    float* dinv = q + (size_t)N_NODES * D_DIM;                 // N fp32
    unsigned short* h0b = (unsigned short*)(dinv + N_NODES);   // N*128 bf16
    unsigned short* kvb = h0b + (size_t)N_NODES * H_DIM;       // N*128 bf16
    unsigned short* hb  = kvb + (size_t)N_NODES * H_DIM;       // N*128 bf16
    unsigned short* xb  = hb + (size_t)N_NODES * H_DIM;        // N*256 bf16
    unsigned short* wfg = xb + (size_t)N_NODES * F_IN;         // 32768 bf16
    unsigned short* wfm = wfg + 32768;                         // 32768 bf16
    unsigned short* wfl = wfm + 32768;                         // 32768 bf16
    int* counts = (int*)(wfl + 32768);            // N
    int* rowptr = counts + N_NODES;               // N+4
    int* cursor = rowptr + N_NODES + 4;           // N
    int* srcs   = cursor + N_NODES;               // E
    int* blockSums = srcs + N_EDGES;              // SCAN_BLK

    const int B = 256;
    // weight fragment shuffles + x conversion
    k_wfrag_gcn<<<128, B, 0, stream>>>(W_gcn, wfg);
    k_wfrag_qkvs<<<128, B, 0, stream>>>(Wm[0], Wm[2], Wm[4], Wm[6], wfm);
    k_wfrag_qkvs<<<128, B, 0, stream>>>(Wl8[0], Wl8[2], Wl8[4], Wl8[6], wfl);
    k_xcvt<<<(N_NODES * F_IN / 8 + B - 1) / B, B, 0, stream>>>(x, xb);

    // CSR build
    k_zero<<<(N_NODES + B - 1) / B, B, 0, stream>>>(counts);
    k_hist<<<(N_EDGES + B - 1) / B, B, 0, stream>>>(dst, counts);
    k_scan1<<<SCAN_BLK, B, 0, stream>>>(counts, rowptr, blockSums);
    k_scan2<<<SCAN_BLK, B, 0, stream>>>(counts, blockSums, rowptr, cursor, dinv);
    k_fill<<<(N_EDGES + B - 1) / B, B, 0, stream>>>(src, dst, cursor, srcs);

    // GCN
    k_gemm_gcn_mfma<<<GEMM_BLK, B, 0, stream>>>(xb, wfg, dinv, h0b);
    k_gcn_gather<<<(N_NODES + 15) / 16, B, 0, stream>>>(h0b, rowptr, srcs, dinv, b_gcn, hb);

    // two TransformerConvs
    for (int c = 0; c < 2; ++c) {
        const float* const* Wset = (c == 0) ? Wm : Wl8;
        float* outp = (c == 0) ? mu_out : ls_out;
        k_qkvs_mfma<<<GEMM_BLK, B, 0, stream>>>(hb, (c == 0) ? wfm : wfl,
                                                Wset[1], Wset[3], Wset[5], Wset[7],
                                                q, kvb, outp);
        k_attn<<<(N_NODES + 3) / 4, B, 0, stream>>>(q, kvb, rowptr, srcs, outp, c);
    }
}

// Round 7
// 233.004 us; speedup vs baseline: 7.5164x; 1.3286x over previous
//
#include <hip/hip_runtime.h>
#include <math.h>

#define N_NODES 50000
#define N_EDGES 800000
#define F_IN    256
#define H_DIM   128
#define D_DIM   64
#define MAX_LOGSTD 10.0f
#define LEAKY_SLOPE 0.01f

#define NB       196            // dst buckets (dst>>8), 196*256 >= N_NODES
#define BCAP     5000           // per-bucket staging capacity (mean 4082, +14 sigma)
#define GEMM_BLK 782            // ceil(N_NODES/64)

using bf16x8 = __attribute__((ext_vector_type(8))) short;
using f32x4  = __attribute__((ext_vector_type(4))) float;

// ---------- bf16 helpers (RNE pack, shift unpack) ----------
__device__ inline float bflo(unsigned u) { return __uint_as_float(u << 16); }
__device__ inline float bfhi(unsigned u) { return __uint_as_float(u & 0xFFFF0000u); }
__device__ inline unsigned short f2bf(float f) {
    unsigned u = __float_as_uint(f);
    u += 0x7FFFu + ((u >> 16) & 1u);
    return (unsigned short)(u >> 16);
}
__device__ inline unsigned pack2(float a, float b) {
    return (unsigned)f2bf(a) | ((unsigned)f2bf(b) << 16);
}

// ======= prep: weight fragment shuffles (3 mats) + bucket cursor init =======
// blocks [0,128): wfg from W_gcn ; [128,256): wfm ; [256,384): wfl ; 384: init
__global__ void k_prep(const float* __restrict__ Wg,
                       const float* __restrict__ Wq0, const float* __restrict__ Wk0,
                       const float* __restrict__ Wv0, const float* __restrict__ Ws0,
                       const float* __restrict__ Wq1, const float* __restrict__ Wk1,
                       const float* __restrict__ Wv1, const float* __restrict__ Ws1,
                       unsigned short* __restrict__ wfg, unsigned short* __restrict__ wfm,
                       unsigned short* __restrict__ wfl, int* __restrict__ gCursor) {
    int blk = blockIdx.x, t = threadIdx.x;
    if (blk == 384) { if (t < 256) gCursor[t] = 0; return; }
    int grp = blk >> 7;                    // 0:gcn 1:mu 2:ls
    int tid = (blk & 127) * 256 + t;       // 0..32767
    if (grp == 0) {
        int j = tid & 7, ct = (tid >> 3) & 1, ks = (tid >> 4) & 7;
        int l = (tid >> 7) & 63, w = tid >> 13;
        int k = ks * 32 + (l >> 4) * 8 + j;
        int n = w * 32 + ct * 16 + (l & 15);
        wfg[tid] = f2bf(Wg[k * H_DIM + n]);
    } else {
        int j = tid & 7, ct = (tid >> 3) & 3, ks = (tid >> 5) & 3;
        int l = (tid >> 7) & 63, w = tid >> 13;
        int k = ks * 32 + (l >> 4) * 8 + j;
        int n = ct * 16 + (l & 15);
        const float* Wsrc = (grp == 1)
            ? ((w == 0) ? Wq0 : (w == 1) ? Wk0 : (w == 2) ? Wv0 : Ws0)
            : ((w == 0) ? Wq1 : (w == 1) ? Wk1 : (w == 2) ? Wv1 : Ws1);
        unsigned short val = f2bf(Wsrc[k * D_DIM + n]);
        if (grp == 1) wfm[tid] = val; else wfl[tid] = val;
    }
}

// ======= CSR phase A: bucket edges into contiguous staging chunks =======
__global__ __launch_bounds__(256) void k_bucketA(
        const int* __restrict__ src, const int* __restrict__ dst,
        int* __restrict__ gCursor, uint2* __restrict__ staging) {
    __shared__ int cnt[NB];
    __shared__ int base[NB];
    int t = threadIdx.x;
    int e0 = blockIdx.x * 4096;
    for (int i = t; i < NB; i += 256) cnt[i] = 0;
    __syncthreads();
    int s[16], d[16], b[16];
#pragma unroll
    for (int i = 0; i < 16; ++i) {
        int e = e0 + t + i * 256;
        if (e < N_EDGES) {
            s[i] = src[e]; d[i] = dst[e]; b[i] = d[i] >> 8;
            atomicAdd(&cnt[b[i]], 1);
        } else b[i] = -1;
    }
    __syncthreads();
    for (int i = t; i < NB; i += 256) base[i] = atomicAdd(&gCursor[i], cnt[i]);
    __syncthreads();
    for (int i = t; i < NB; i += 256) cnt[i] = 0;
    __syncthreads();
#pragma unroll
    for (int i = 0; i < 16; ++i) {
        if (b[i] >= 0) {
            int lp = atomicAdd(&cnt[b[i]], 1);
            staging[(size_t)b[i] * BCAP + base[b[i]] + lp] =
                make_uint2((unsigned)s[i], (unsigned)d[i]);
        }
    }
}

// ======= CSR phase B: per-bucket dst-hist + scan -> rowptr/dinv; LDS-cursor scatter =======
__global__ __launch_bounds__(256) void k_bucketB(
        const uint2* __restrict__ staging, const int* __restrict__ gCursor,
        int* __restrict__ rowptr, float* __restrict__ dinv, int* __restrict__ srcs) {
    __shared__ int sg[256];
    __shared__ int dcnt[256], doff[256], dcur[256];
    int b = blockIdx.x, t = threadIdx.x;
    // redundant scan of bucket totals -> this bucket's base
    sg[t] = (t < NB) ? gCursor[t] : 0;
    dcnt[t] = 0;
    __syncthreads();
    int n = sg[b];
    for (int off = 1; off < 256; off <<= 1) {
        int u = (t >= off) ? sg[t - off] : 0;
        __syncthreads();
        sg[t] += u;
        __syncthreads();
    }
    int bb = sg[b] - n;                   // exclusive bucket base
    const uint2* st = staging + (size_t)b * BCAP;
    for (int i = t; i < n; i += 256) atomicAdd(&dcnt[(int)st[i].y & 255], 1);
    __syncthreads();
    doff[t] = dcnt[t];
    __syncthreads();
    for (int off = 1; off < 256; off <<= 1) {
        int u = (t >= off) ? doff[t - off] : 0;
        __syncthreads();
        doff[t] += u;
        __syncthreads();
    }
    int excl = doff[t] - dcnt[t];
    int node = b * 256 + t;
    if (node < N_NODES) {
        rowptr[node] = bb + excl;
        dinv[node] = rsqrtf((float)(dcnt[t] + 1));   // +1 self loop
    }
    dcur[t] = bb + excl;
    if (b == 0 && t == 0) rowptr[N_NODES] = N_EDGES;
    __syncthreads();
    for (int i = t; i < n; i += 256) {
        uint2 r = st[i];
        int p = atomicAdd(&dcur[(int)r.y & 255], 1);
        srcs[p] = (int)r.x;
    }
}

// ================= GCN GEMM (MFMA): h0b = bf16((x @ W) * dinv[row]) =================
// 64-row tile x 128 cols, K=256. In-staging fp32->bf16 conversion.
__global__ __launch_bounds__(256) void k_gemm_gcn_mfma(
        const float* __restrict__ x, const unsigned short* __restrict__ wfrag,
        const float* __restrict__ dinv, unsigned short* __restrict__ h0b) {
    __shared__ uint4 sA[64 * 32];          // 64 rows x 256 bf16, XOR-swizzled
    int t = threadIdx.x, l = t & 63, w = t >> 6;
    int r0 = blockIdx.x * 64;
    const bf16x8* Wf = ((const bf16x8*)wfrag) + ((w * 64 + l) << 4);
    bf16x8 bfr[8][2];
#pragma unroll
    for (int ks = 0; ks < 8; ++ks) {
        bfr[ks][0] = Wf[ks * 2];
        bfr[ks][1] = Wf[ks * 2 + 1];
    }
    const float4* xg = (const float4*)x;
#pragma unroll
    for (int p = 0; p < 8; ++p) {
        int idx = t + p * 256;
        int row = idx >> 5, c16 = idx & 31;
        int grow = min(r0 + row, N_NODES - 1);
        float4 a0 = xg[(size_t)grow * 64 + c16 * 2];
        float4 a1 = xg[(size_t)grow * 64 + c16 * 2 + 1];
        uint4 o;
        o.x = pack2(a0.x, a0.y); o.y = pack2(a0.z, a0.w);
        o.z = pack2(a1.x, a1.y); o.w = pack2(a1.z, a1.w);
        sA[row * 32 + (c16 ^ (row & 7))] = o;
    }
    __syncthreads();
    f32x4 zero = {0.f, 0.f, 0.f, 0.f};
    f32x4 acc[4][2];
#pragma unroll
    for (int rt = 0; rt < 4; ++rt) { acc[rt][0] = zero; acc[rt][1] = zero; }
    int lr = l & 15, lh = l >> 4;
#pragma unroll
    for (int ks = 0; ks < 8; ++ks) {
        bf16x8 a[4];
#pragma unroll
        for (int rt = 0; rt < 4; ++rt) {
            int row = rt * 16 + lr;
            int c4 = (ks * 4 + lh) ^ (row & 7);
            a[rt] = ((const bf16x8*)sA)[row * 32 + c4];
        }
#pragma unroll
        for (int rt = 0; rt < 4; ++rt) {
            acc[rt][0] = __builtin_amdgcn_mfma_f32_16x16x32_bf16(a[rt], bfr[ks][0], acc[rt][0], 0, 0, 0);
            acc[rt][1] = __builtin_amdgcn_mfma_f32_16x16x32_bf16(a[rt], bfr[ks][1], acc[rt][1], 0, 0, 0);
        }
    }
#pragma unroll
    for (int rt = 0; rt < 4; ++rt)
#pragma unroll
        for (int j = 0; j < 4; ++j) {
            int row = r0 + rt * 16 + lh * 4 + j;
            if (row < N_NODES) {
                float dv = dinv[row];
                size_t base = (size_t)row * H_DIM + w * 32 + lr;
                h0b[base]      = f2bf(acc[rt][0][j] * dv);
                h0b[base + 16] = f2bf(acc[rt][1][j] * dv);
            }
        }
}

// ================= GCN aggregate: bf16 gather -> bf16 h =================
__global__ void k_gcn_gather(const unsigned short* __restrict__ h0b,
                             const int* __restrict__ rowptr, const int* __restrict__ srcs,
                             const float* __restrict__ dinv, const float* __restrict__ b,
                             unsigned short* __restrict__ hb) {
    int t = threadIdx.x;
    int node = blockIdx.x * 16 + (t >> 4);
    int sl = t & 15;
    if (node >= N_NODES) return;
    uint4 U = ((const uint4*)(h0b + (size_t)node * H_DIM))[sl];   // self loop
    float acc[8] = {bflo(U.x), bfhi(U.x), bflo(U.y), bfhi(U.y),
                    bflo(U.z), bfhi(U.z), bflo(U.w), bfhi(U.w)};
    int beg = rowptr[node], end = rowptr[node + 1];
    for (int p = beg; p < end; ++p) {
        int s = srcs[p];
        uint4 V = ((const uint4*)(h0b + (size_t)s * H_DIM))[sl];
        acc[0] += bflo(V.x); acc[1] += bfhi(V.x);
        acc[2] += bflo(V.y); acc[3] += bfhi(V.y);
        acc[4] += bflo(V.z); acc[5] += bfhi(V.z);
        acc[6] += bflo(V.w); acc[7] += bfhi(V.w);
    }
    float dv = dinv[node];
    float out[8];
#pragma unroll
    for (int i = 0; i < 8; ++i) {
        float val = acc[i] * dv + b[sl * 8 + i];
        out[i] = (val >= 0.f) ? val : LEAKY_SLOPE * val;
    }
    uint4 o;
    o.x = pack2(out[0], out[1]); o.y = pack2(out[2], out[3]);
    o.z = pack2(out[4], out[5]); o.w = pack2(out[6], out[7]);
    ((uint4*)(hb + (size_t)node * H_DIM))[sl] = o;
}

// ============ q,k,v,skip GEMM (MFMA): wave w -> {q, k, v, skip} ============
__global__ __launch_bounds__(256) void k_qkvs_mfma(
        const unsigned short* __restrict__ hb, const unsigned short* __restrict__ wfrag,
        const float* __restrict__ bq, const float* __restrict__ bk,
        const float* __restrict__ bv, const float* __restrict__ bs,
        float* __restrict__ q, unsigned short* __restrict__ kvb,
        float* __restrict__ outp) {
    __shared__ uint4 sA[64 * 16];          // 64 rows x 128 bf16, XOR-swizzled
    int t = threadIdx.x, l = t & 63, w = t >> 6;
    int r0 = blockIdx.x * 64;
    const bf16x8* Wf = ((const bf16x8*)wfrag) + ((w * 64 + l) << 4);
    bf16x8 bfr[4][4];
#pragma unroll
    for (int ks = 0; ks < 4; ++ks)
#pragma unroll
        for (int ct = 0; ct < 4; ++ct) bfr[ks][ct] = Wf[ks * 4 + ct];
    const uint4* hg = (const uint4*)hb;
#pragma unroll
    for (int p = 0; p < 4; ++p) {
        int idx = t + p * 256;
        int row = idx >> 4, c16 = idx & 15;
        int grow = min(r0 + row, N_NODES - 1);
        sA[row * 16 + (c16 ^ (row & 7))] = hg[(size_t)grow * 16 + c16];
    }
    __syncthreads();
    f32x4 zero = {0.f, 0.f, 0.f, 0.f};
    f32x4 acc[4][4];
#pragma unroll
    for (int rt = 0; rt < 4; ++rt)
#pragma unroll
        for (int ct = 0; ct < 4; ++ct) acc[rt][ct] = zero;
    int lr = l & 15, lh = l >> 4;
#pragma unroll
    for (int ks = 0; ks < 4; ++ks) {
        bf16x8 a[4];
#pragma unroll
        for (int rt = 0; rt < 4; ++rt) {
            int row = rt * 16 + lr;
            int c4 = (ks * 4 + lh) ^ (row & 7);
            a[rt] = ((const bf16x8*)sA)[row * 16 + c4];
        }
#pragma unroll
        for (int rt = 0; rt < 4; ++rt)
#pragma unroll
            for (int ct = 0; ct < 4; ++ct)
                acc[rt][ct] = __builtin_amdgcn_mfma_f32_16x16x32_bf16(a[rt], bfr[ks][ct], acc[rt][ct], 0, 0, 0);
    }
    const float* bias = (w == 0) ? bq : (w == 1) ? bk : (w == 2) ? bv : bs;
    float bcol[4];
#pragma unroll
    for (int ct = 0; ct < 4; ++ct) bcol[ct] = bias[ct * 16 + lr];
#pragma unroll
    for (int rt = 0; rt < 4; ++rt)
#pragma unroll
        for (int j = 0; j < 4; ++j) {
            int row = r0 + rt * 16 + lh * 4 + j;
            if (row >= N_NODES) continue;
            float v0 = acc[rt][0][j] + bcol[0];
            float v1 = acc[rt][1][j] + bcol[1];
            float v2 = acc[rt][2][j] + bcol[2];
            float v3 = acc[rt][3][j] + bcol[3];
            if (w == 0) {
                float* qp = q + (size_t)row * D_DIM + lr;
                qp[0] = v0; qp[16] = v1; qp[32] = v2; qp[48] = v3;
            } else if (w == 1) {
                unsigned short* kp = kvb + (size_t)row * 128 + lr;
                kp[0] = f2bf(v0); kp[16] = f2bf(v1); kp[32] = f2bf(v2); kp[48] = f2bf(v3);
            } else if (w == 2) {
                unsigned short* vp = kvb + (size_t)row * 128 + 64 + lr;
                vp[0] = f2bf(v0); vp[16] = f2bf(v1); vp[32] = f2bf(v2); vp[48] = f2bf(v3);
            } else {
                float* op = outp + (size_t)row * D_DIM + lr;
                op[0] = v0; op[16] = v1; op[32] = v2; op[48] = v3;
            }
        }
}

// ================= fused attention: wave/node, bf16 kv gather =========
__global__ void k_attn(const float* __restrict__ q, const unsigned short* __restrict__ kvb,
                       const int* __restrict__ rowptr, const int* __restrict__ srcs,
                       float* __restrict__ outp, int clampFlag) {
    int t = threadIdx.x;
    int node = blockIdx.x * 4 + (t >> 6);
    int l = t & 63;
    if (node >= N_NODES) return;
    int g = l >> 4, sl = l & 15;
    float4 q4 = ((const float4*)(q + (size_t)node * D_DIM))[sl];
    int beg = rowptr[node], end = rowptr[node + 1];
    int deg = end - beg;
    int p0 = beg + ((deg * g) >> 2);
    int p1 = beg + ((deg * (g + 1)) >> 2);
    float m = -INFINITY, den = 0.f;
    float4 acc = make_float4(0.f, 0.f, 0.f, 0.f);
    for (int p = p0; p < p1; ++p) {
        int s = srcs[p];
        const unsigned short* kv = kvb + (size_t)s * 128;
        uint2 ku = *(const uint2*)(kv + sl * 4);
        uint2 vu = *(const uint2*)(kv + 64 + sl * 4);
        float d = q4.x * bflo(ku.x);
        d = fmaf(q4.y, bfhi(ku.x), d);
        d = fmaf(q4.z, bflo(ku.y), d);
        d = fmaf(q4.w, bfhi(ku.y), d);
        d += __shfl_xor(d, 1);
        d += __shfl_xor(d, 2);
        d += __shfl_xor(d, 4);
        d += __shfl_xor(d, 8);
        float alpha = d * 0.125f;                 // / sqrt(64)
        float mn = fmaxf(m, alpha);
        float sc = __expf(m - mn);                // 0 on first edge
        float ex = __expf(alpha - mn);
        den = den * sc + ex;
        acc.x = acc.x * sc + ex * bflo(vu.x);
        acc.y = acc.y * sc + ex * bfhi(vu.x);
        acc.z = acc.z * sc + ex * bflo(vu.y);
        acc.w = acc.w * sc + ex * bfhi(vu.y);
        m = mn;
    }
    float M = m;
    M = fmaxf(M, __shfl_xor(M, 16));
    M = fmaxf(M, __shfl_xor(M, 32));
    float sc = (m == -INFINITY) ? 0.f : __expf(m - M);
    den *= sc;
    acc.x *= sc; acc.y *= sc; acc.z *= sc; acc.w *= sc;
    den += __shfl_xor(den, 16);
    den += __shfl_xor(den, 32);
    acc.x += __shfl_xor(acc.x, 16); acc.x += __shfl_xor(acc.x, 32);
    acc.y += __shfl_xor(acc.y, 16); acc.y += __shfl_xor(acc.y, 32);
    acc.z += __shfl_xor(acc.z, 16); acc.z += __shfl_xor(acc.z, 32);
    acc.w += __shfl_xor(acc.w, 16); acc.w += __shfl_xor(acc.w, 32);
    if (g == 0) {
        float inv = 1.f / (den + 1e-16f);
        float4 sk = ((float4*)outp)[node * 16 + sl];
        float4 o = make_float4(acc.x * inv + sk.x, acc.y * inv + sk.y,
                               acc.z * inv + sk.z, acc.w * inv + sk.w);
        if (clampFlag) {
            o.x = fminf(o.x, MAX_LOGSTD); o.y = fminf(o.y, MAX_LOGSTD);
            o.z = fminf(o.z, MAX_LOGSTD); o.w = fminf(o.w, MAX_LOGSTD);
        }
        ((float4*)outp)[node * 16 + sl] = o;
    }
}

// ================= launch =================
extern "C" void kernel_launch(void* const* d_in, const int* in_sizes, int n_in,
                              void* d_out, int out_size, void* d_ws, size_t ws_size,
                              hipStream_t stream) {
    const float* x     = (const float*)d_in[0];
    const int*   ei    = (const int*)d_in[1];
    const int*   src   = ei;
    const int*   dst   = ei + N_EDGES;
    const float* W_gcn = (const float*)d_in[2];
    const float* b_gcn = (const float*)d_in[3];
    const float* Wm[8]; const float* Wl8[8];
    for (int i = 0; i < 8; ++i) { Wm[i] = (const float*)d_in[4 + i]; Wl8[i] = (const float*)d_in[12 + i]; }

    float* out    = (float*)d_out;
    float* mu_out = out;
    float* ls_out = out + N_NODES * D_DIM;

    float* ws   = (float*)d_ws;
    float* q    = ws;                                          // N*64 fp32
    float* dinv = q + (size_t)N_NODES * D_DIM;                 // N fp32
    unsigned short* h0b = (unsigned short*)(dinv + N_NODES);   // N*128 bf16
    unsigned short* kvb = h0b + (size_t)N_NODES * H_DIM;       // N*128 bf16
    unsigned short* hb  = kvb + (size_t)N_NODES * H_DIM;       // N*128 bf16
    unsigned short* wfg = hb + (size_t)N_NODES * H_DIM;        // 32768 bf16
    unsigned short* wfm = wfg + 32768;
    unsigned short* wfl = wfm + 32768;
    int* rowptr  = (int*)(wfl + 32768);           // N+4
    int* srcs    = rowptr + N_NODES + 4;          // E
    int* gCursor = srcs + N_EDGES;                // 256
    uint2* staging = (uint2*)(gCursor + 256);     // NB*BCAP (8B aligned)

    const int B = 256;
    // prep (wfrag x3 + gCursor zero) and CSR build
    k_prep<<<385, B, 0, stream>>>(W_gcn, Wm[0], Wm[2], Wm[4], Wm[6],
                                  Wl8[0], Wl8[2], Wl8[4], Wl8[6],
                                  wfg, wfm, wfl, gCursor);
    k_bucketA<<<(N_EDGES + 4095) / 4096, B, 0, stream>>>(src, dst, gCursor, staging);
    k_bucketB<<<NB, B, 0, stream>>>(staging, gCursor, rowptr, dinv, srcs);

    // GCN
    k_gemm_gcn_mfma<<<GEMM_BLK, B, 0, stream>>>(x, wfg, dinv, h0b);
    k_gcn_gather<<<(N_NODES + 15) / 16, B, 0, stream>>>(h0b, rowptr, srcs, dinv, b_gcn, hb);

    // two TransformerConvs
    for (int c = 0; c < 2; ++c) {
        const float* const* Wset = (c == 0) ? Wm : Wl8;
        float* outp = (c == 0) ? mu_out : ls_out;
        k_qkvs_mfma<<<GEMM_BLK, B, 0, stream>>>(hb, (c == 0) ? wfm : wfl,
                                                Wset[1], Wset[3], Wset[5], Wset[7],
                                                q, kvb, outp);
        k_attn<<<(N_NODES + 3) / 4, B, 0, stream>>>(q, kvb, rowptr, srcs, outp, c);
    }
}